// Round 5
// baseline (2555.155 us; speedup 1.0000x reference)
//
#include <hip/hip_runtime.h>

#define EPS 1e-16f

// ---------- bf16 <-> fp32 (internal storage only) ----------
__device__ __forceinline__ float b2f(unsigned short u) {
    return __uint_as_float(((unsigned)u) << 16);
}
__device__ __forceinline__ unsigned short f2b(float f) {
    unsigned u = __float_as_uint(f);
    u += 0x7fffu + ((u >> 16) & 1u);  // round-to-nearest-even
    return (unsigned short)(u >> 16);
}

// ---------------------------- CSR build ----------------------------
__global__ void init_deg_kernel(int* deg, int N) {
    int i = blockIdx.x * blockDim.x + threadIdx.x;
    if (i < N) deg[i] = 1;  // self-loop
}

__global__ void hist_kernel(const int* __restrict__ ei, int E, int N, int* deg) {
    int e = blockIdx.x * blockDim.x + threadIdx.x;
    if (e < E) {
        int d = ei[E + e];
        if ((unsigned)d < (unsigned)N) atomicAdd(&deg[d], 1);
    }
}

// one wave, chunked sequential scan: rowst[0]=0, rowst[i+1]=sum(deg[0..i])
__global__ void scan_kernel(const int* __restrict__ deg, int* __restrict__ rowst,
                            int N) {
    __shared__ int psum[65];
    int t = threadIdx.x;  // 64 threads
    int chunk = (N + 63) / 64;
    int lo = t * chunk;
    int hi = lo + chunk;
    if (lo > N) lo = N;
    if (hi > N) hi = N;
    int s = 0;
    for (int i = lo; i < hi; i++) s += deg[i];
    psum[t + 1] = s;
    __syncthreads();
    if (t == 0) {
        psum[0] = 0;
        for (int i = 1; i <= 64; i++) psum[i] += psum[i - 1];
        rowst[0] = 0;
    }
    __syncthreads();
    int run = psum[t];
    for (int i = lo; i < hi; i++) {
        run += deg[i];
        rowst[i + 1] = run;
    }
}

__global__ void selfloop_kernel(const int* __restrict__ rowst, int* ids,
                                int* cursor, int N, int E) {
    int n = blockIdx.x * blockDim.x + threadIdx.x;
    if (n < N) {
        ids[rowst[n]] = E + n;  // self-loop edge id
        cursor[n] = rowst[n] + 1;
    }
}

__global__ void scatter_kernel(const int* __restrict__ ei, int E, int N,
                               int* cursor, int* ids) {
    int e = blockIdx.x * blockDim.x + threadIdx.x;
    if (e < E) {
        int d = ei[E + e];
        if ((unsigned)d < (unsigned)N) {
            int p = atomicAdd(&cursor[d], 1);
            ids[p] = e;
        }
    }
}

// ---------------------------- GEMMs ----------------------------
// h = x @ W1: x [N,11] fp32, W [11,1024] fp32 -> h [N,1024] bf16. Flat 1-D.
__global__ void gemm_k11(const float* __restrict__ x, const float* __restrict__ W,
                         unsigned short* __restrict__ h, int N) {
    int i = blockIdx.x * blockDim.x + threadIdx.x;  // over N*1024
    if (i >= N * 1024) return;
    int n = i >> 10, j = i & 1023;
    float acc = 0.f;
#pragma unroll
    for (int k = 0; k < 11; k++) acc += x[n * 11 + k] * W[k * 1024 + j];
    h[i] = f2b(acc);
}

// tiled GEMM: A [M,K] bf16 (internal), B [K,N] fp32 (input), C [M,N] bf16.
// N%64==0, K%16==0.
__global__ __launch_bounds__(256) void gemm_tiled(
    const unsigned short* __restrict__ A, const float* __restrict__ B,
    unsigned short* __restrict__ C, int M, int N, int K) {
    __shared__ float As[16][68];  // [k][row], padded for float4 alignment
    __shared__ float Bs[16][64];
    int t = threadIdx.x;
    int bm = blockIdx.y * 64, bn = blockIdx.x * 64;
    int ar = t >> 2, ac4 = (t & 3) << 2;   // A tile: 64 rows x 16 k
    int br = t >> 4, bc4 = (t & 15) << 2;  // B tile: 16 k x 64 cols
    int tx = t & 15, ty = t >> 4;
    float acc[4][4] = {};
    int arow = bm + ar;
    bool avalid = arow < M;
    const unsigned short* Aptr = avalid ? (A + (size_t)arow * K + ac4) : A;
    for (int k0 = 0; k0 < K; k0 += 16) {
        ushort4 av = avalid ? *(const ushort4*)(Aptr + k0) : make_ushort4(0, 0, 0, 0);
        float4 bv = *(const float4*)(B + (size_t)(k0 + br) * N + bn + bc4);
        As[ac4 + 0][ar] = b2f(av.x);
        As[ac4 + 1][ar] = b2f(av.y);
        As[ac4 + 2][ar] = b2f(av.z);
        As[ac4 + 3][ar] = b2f(av.w);
        *(float4*)&Bs[br][bc4] = bv;
        __syncthreads();
#pragma unroll
        for (int k = 0; k < 16; k++) {
            float4 a = *(const float4*)&As[k][ty * 4];
            float4 b = *(const float4*)&Bs[k][tx * 4];
            acc[0][0] += a.x * b.x; acc[0][1] += a.x * b.y; acc[0][2] += a.x * b.z; acc[0][3] += a.x * b.w;
            acc[1][0] += a.y * b.x; acc[1][1] += a.y * b.y; acc[1][2] += a.y * b.z; acc[1][3] += a.y * b.w;
            acc[2][0] += a.z * b.x; acc[2][1] += a.z * b.y; acc[2][2] += a.z * b.z; acc[2][3] += a.z * b.w;
            acc[3][0] += a.w * b.x; acc[3][1] += a.w * b.y; acc[3][2] += a.w * b.z; acc[3][3] += a.w * b.w;
        }
        __syncthreads();
    }
#pragma unroll
    for (int i = 0; i < 4; i++) {
        int row = bm + ty * 4 + i;
        if (row < M) {
            ushort4 o = make_ushort4(f2b(acc[i][0]), f2b(acc[i][1]),
                                     f2b(acc[i][2]), f2b(acc[i][3]));
            *(ushort4*)&C[(size_t)row * N + bn + tx * 4] = o;
        }
    }
}

// ---------------------------- attention logits ----------------------------
// one wave per (n,h): als[n,h] = sum_c h[n,h,c]*a_s[h,c]; same for a_d
__global__ void al_kernel(const unsigned short* __restrict__ h,
                          const float* __restrict__ a_s,
                          const float* __restrict__ a_d, float* __restrict__ als,
                          float* __restrict__ ald, int NH, int H, int C) {
    int wave = (int)((blockIdx.x * blockDim.x + threadIdx.x) >> 6);
    int lane = threadIdx.x & 63;
    if (wave >= NH) return;
    int n = wave / H, hh = wave % H;
    const unsigned short* hp = h + (size_t)n * H * C + (size_t)hh * C;
    const float* as = a_s + hh * C;
    const float* ad = a_d + hh * C;
    float s = 0.f, d = 0.f;
    for (int c = lane; c < C; c += 64) {
        float v = b2f(hp[c]);
        s += v * as[c];
        d += v * ad[c];
    }
    for (int o = 32; o; o >>= 1) {
        s += __shfl_xor(s, o);
        d += __shfl_xor(d, o);
    }
    if (lane == 0) { als[wave] = s; ald[wave] = d; }
}

// ---------------------- fused softmax + aggregation ----------------------
// one block per dst node n; 3 passes over its in-edge list (self-loop incl.):
//   1) m = max leaky02(als[src]+ald[n])  (init = self-loop logit, no sentinel)
//   2) den = sum exp(v-m)   3) acc = sum alpha*h[src];  out = leaky01(acc+bias)
template <int H, int C, int TPB>
__global__ void agg_fused(const unsigned short* __restrict__ hin,
                          const float* __restrict__ als,
                          const float* __restrict__ ald,
                          const int* __restrict__ rowst,
                          const int* __restrict__ ids,
                          const int* __restrict__ ei,
                          const float* __restrict__ bias,
                          unsigned short* __restrict__ out, int E, int N) {
    constexpr int HC = H * C;
    constexpr int PER = HC / TPB;
    int n = blockIdx.x;
    int t = threadIdx.x;
    int start = rowst[n], end = rowst[n + 1];

    int myh[PER];
    float aldv[PER], m[PER];
#pragma unroll
    for (int j = 0; j < PER; j++) {
        myh[j] = (t + j * TPB) / C;
        aldv[j] = ald[n * H + myh[j]];
        float v0 = als[n * H + myh[j]] + aldv[j];  // self-loop logit
        m[j] = v0 > 0.f ? v0 : 0.2f * v0;
    }
    // pass 1: max
    for (int idx = start; idx < end; ++idx) {
        int e = ids[idx];
        int s = (e < E) ? ei[e] : n;
        if ((unsigned)s >= (unsigned)N) s = n;
#pragma unroll
        for (int j = 0; j < PER; j++) {
            float v = als[s * H + myh[j]] + aldv[j];
            v = v > 0.f ? v : 0.2f * v;
            m[j] = fmaxf(m[j], v);
        }
    }
    // pass 2: denominator
    float den[PER];
#pragma unroll
    for (int j = 0; j < PER; j++) den[j] = 0.f;
    for (int idx = start; idx < end; ++idx) {
        int e = ids[idx];
        int s = (e < E) ? ei[e] : n;
        if ((unsigned)s >= (unsigned)N) s = n;
#pragma unroll
        for (int j = 0; j < PER; j++) {
            float v = als[s * H + myh[j]] + aldv[j];
            v = v > 0.f ? v : 0.2f * v;
            den[j] += expf(v - m[j]);
        }
    }
    float inv[PER];
#pragma unroll
    for (int j = 0; j < PER; j++) inv[j] = 1.0f / (den[j] + EPS);
    // pass 3: accumulate
    float acc[PER];
#pragma unroll
    for (int j = 0; j < PER; j++) acc[j] = 0.f;
    for (int idx = start; idx < end; ++idx) {
        int e = ids[idx];
        int s = (e < E) ? ei[e] : n;
        if ((unsigned)s >= (unsigned)N) s = n;
        const unsigned short* hp = hin + (size_t)s * HC;
#pragma unroll
        for (int j = 0; j < PER; j++) {
            int c = t + j * TPB;
            float v = als[s * H + myh[j]] + aldv[j];
            v = v > 0.f ? v : 0.2f * v;
            acc[j] += expf(v - m[j]) * inv[j] * b2f(hp[c]);
        }
    }
#pragma unroll
    for (int j = 0; j < PER; j++) {
        int c = t + j * TPB;
        float v = acc[j] + bias[c];
        out[(size_t)n * HC + c] = f2b(v > 0.f ? v : 0.01f * v);
    }
}

// ---------------------------- pooling + head ----------------------------
__global__ void pool_init_kernel(float* pool, float* cnt, int G) {
    int i = blockIdx.x * blockDim.x + threadIdx.x;
    if (i < G * 128) pool[i] = 0.f;
    if (i < G) cnt[i] = 0.f;
}

__global__ void pool_accum_kernel(const unsigned short* __restrict__ h3,
                                  const int* __restrict__ batch, float* pool,
                                  float* cnt, int N, int G) {
    int i = blockIdx.x * blockDim.x + threadIdx.x;
    if (i >= N * 128) return;
    int n = i >> 7, c = i & 127;
    int g = batch[n];
    if ((unsigned)g >= (unsigned)G) return;
    atomicAdd(&pool[g * 128 + c], b2f(h3[i]));
    if (c == 0) atomicAdd(&cnt[g], 1.0f);
}

__global__ void final_out_kernel(const float* __restrict__ pool,
                                 const float* __restrict__ cnt,
                                 const float* __restrict__ Wout,
                                 const float* __restrict__ bout,
                                 float* __restrict__ out) {
    int g = blockIdx.x;
    int t = threadIdx.x;  // 128 threads
    float v = pool[g * 128 + t] * Wout[t];
    for (int o = 32; o; o >>= 1) v += __shfl_xor(v, o);
    __shared__ float partial[2];
    if ((t & 63) == 0) partial[t >> 6] = v;
    __syncthreads();
    if (t == 0) {
        float s = partial[0] + partial[1];
        float c = cnt[g];
        c = c > 1.f ? c : 1.f;
        out[g] = s / c + bout[0];
    }
}

// ---------------------------- host orchestration ----------------------------
extern "C" void kernel_launch(void* const* d_in, const int* in_sizes, int n_in,
                              void* d_out, int out_size, void* d_ws,
                              size_t ws_size, hipStream_t stream) {
    // fp32 inputs (bf16-rounded values), int32 indices, fp32 output.
    const float* x = (const float*)d_in[0];
    const int* ei = (const int*)d_in[1];
    const int* batch = (const int*)d_in[2];
    const float* W1 = (const float*)d_in[3];
    const float* a1s = (const float*)d_in[4];
    const float* a1d = (const float*)d_in[5];
    const float* b1 = (const float*)d_in[6];
    const float* W2 = (const float*)d_in[7];
    const float* a2s = (const float*)d_in[8];
    const float* a2d = (const float*)d_in[9];
    const float* b2 = (const float*)d_in[10];
    const float* W3 = (const float*)d_in[11];
    const float* a3s = (const float*)d_in[12];
    const float* a3d = (const float*)d_in[13];
    const float* b3 = (const float*)d_in[14];
    const float* Wout = (const float*)d_in[15];
    const float* bout = (const float*)d_in[16];
    float* out = (float*)d_out;

    const int N = in_sizes[0] / 11;
    const int E = in_sizes[1] / 2;
    const int Etot = E + N;
    const int G = out_size;

    char* ws = (char*)d_ws;
    size_t off = 0;
    auto alloc = [&](size_t bytes) -> void* {
        void* p = ws + off;
        off += (bytes + 255) & ~(size_t)255;
        return p;
    };
    // bf16 internal feature buffers (~205MB total, proven within ws_size)
    unsigned short* buf1 = (unsigned short*)alloc((size_t)N * 1024 * 2);  // h
    unsigned short* buf2 = (unsigned short*)alloc((size_t)N * 1024 * 2);  // out
    float* als = (float*)alloc((size_t)N * 8 * 4);
    float* ald = (float*)alloc((size_t)N * 8 * 4);
    int* rowst = (int*)alloc((size_t)(N + 1) * 4);
    int* cursor = (int*)alloc((size_t)N * 4);
    int* ids = (int*)alloc((size_t)Etot * 4);
    float* pool = (float*)alloc((size_t)G * 128 * 4);
    float* cnt = (float*)alloc((size_t)G * 4);
    int* deg = (int*)alloc((size_t)N * 4);

    int nb = (N + 255) / 256;
    int eb = (E + 255) / 256;

    // ---- CSR by dst (self-loop id = E+n at row head) ----
    init_deg_kernel<<<nb, 256, 0, stream>>>(deg, N);
    hist_kernel<<<eb, 256, 0, stream>>>(ei, E, N, deg);
    scan_kernel<<<1, 64, 0, stream>>>(deg, rowst, N);
    selfloop_kernel<<<nb, 256, 0, stream>>>(rowst, ids, cursor, N, E);
    scatter_kernel<<<eb, 256, 0, stream>>>(ei, E, N, cursor, ids);

    // ---- Layer 1: x [N,11] -> h1=buf1 [N,1024]; H=8,C=128 -> out1=buf2 ----
    gemm_k11<<<(N * 1024 + 255) / 256, 256, 0, stream>>>(x, W1, buf1, N);
    al_kernel<<<(N * 8 + 3) / 4, 256, 0, stream>>>(buf1, a1s, a1d, als, ald,
                                                   N * 8, 8, 128);
    agg_fused<8, 128, 256><<<N, 256, 0, stream>>>(buf1, als, ald, rowst, ids,
                                                  ei, b1, buf2, E, N);

    // ---- Layer 2: out1 [N,1024] @ W2 -> h2=buf1 [N,512]; H=8,C=64 ----
    gemm_tiled<<<dim3(512 / 64, (N + 63) / 64), 256, 0, stream>>>(buf2, W2, buf1,
                                                                  N, 512, 1024);
    al_kernel<<<(N * 8 + 3) / 4, 256, 0, stream>>>(buf1, a2s, a2d, als, ald,
                                                   N * 8, 8, 64);
    agg_fused<8, 64, 256><<<N, 256, 0, stream>>>(buf1, als, ald, rowst, ids,
                                                 ei, b2, buf2, E, N);

    // ---- Layer 3: out2 [N,512] @ W3 -> h3=buf1 [N,128]; H=4,C=32 ----
    gemm_tiled<<<dim3(128 / 64, (N + 63) / 64), 256, 0, stream>>>(buf2, W3, buf1,
                                                                  N, 128, 512);
    al_kernel<<<(N * 4 + 3) / 4, 256, 0, stream>>>(buf1, a3s, a3d, als, ald,
                                                   N * 4, 4, 32);
    agg_fused<4, 32, 128><<<N, 128, 0, stream>>>(buf1, als, ald, rowst, ids,
                                                 ei, b3, buf2, E, N);

    // ---- mean-pool per graph + output head ----
    pool_init_kernel<<<(G * 128 + 255) / 256, 256, 0, stream>>>(pool, cnt, G);
    pool_accum_kernel<<<(N * 128 + 255) / 256, 256, 0, stream>>>(buf2, batch,
                                                                 pool, cnt, N, G);
    final_out_kernel<<<G, 128, 0, stream>>>(pool, cnt, Wout, bout, out);
}

// Round 6
// 1362.879 us; speedup vs baseline: 1.8748x; 1.8748x over previous
//
#include <hip/hip_runtime.h>

#define EPS 1e-16f

typedef __attribute__((ext_vector_type(8))) short short8;
typedef __attribute__((ext_vector_type(4))) float f32x4;

// ---------- bf16 <-> fp32 (internal storage only) ----------
__device__ __forceinline__ float b2f(unsigned short u) {
    return __uint_as_float(((unsigned)u) << 16);
}
__device__ __forceinline__ unsigned short f2b(float f) {
    unsigned u = __float_as_uint(f);
    u += 0x7fffu + ((u >> 16) & 1u);  // round-to-nearest-even
    return (unsigned short)(u >> 16);
}

// ---------------------------- CSR build ----------------------------
__global__ void init_deg_kernel(int* deg, int N) {
    int i = blockIdx.x * blockDim.x + threadIdx.x;
    if (i < N) deg[i] = 1;  // self-loop
}

__global__ void hist_kernel(const int* __restrict__ ei, int E, int N, int* deg) {
    int e = blockIdx.x * blockDim.x + threadIdx.x;
    if (e < E) {
        int d = ei[E + e];
        if ((unsigned)d < (unsigned)N) atomicAdd(&deg[d], 1);
    }
}

// one wave, chunked sequential scan
__global__ void scan_kernel(const int* __restrict__ deg, int* __restrict__ rowst,
                            int N) {
    __shared__ int psum[65];
    int t = threadIdx.x;  // 64 threads
    int chunk = (N + 63) / 64;
    int lo = t * chunk, hi = lo + chunk;
    if (lo > N) lo = N;
    if (hi > N) hi = N;
    int s = 0;
    for (int i = lo; i < hi; i++) s += deg[i];
    psum[t + 1] = s;
    __syncthreads();
    if (t == 0) {
        psum[0] = 0;
        for (int i = 1; i <= 64; i++) psum[i] += psum[i - 1];
        rowst[0] = 0;
    }
    __syncthreads();
    int run = psum[t];
    for (int i = lo; i < hi; i++) {
        run += deg[i];
        rowst[i + 1] = run;
    }
}

__global__ void selfloop_kernel(const int* __restrict__ rowst, int* ids,
                                int* cursor, int N, int E) {
    int n = blockIdx.x * blockDim.x + threadIdx.x;
    if (n < N) {
        ids[rowst[n]] = E + n;  // self-loop edge id
        cursor[n] = rowst[n] + 1;
    }
}

__global__ void scatter_kernel(const int* __restrict__ ei, int E, int N,
                               int* cursor, int* ids) {
    int e = blockIdx.x * blockDim.x + threadIdx.x;
    if (e < E) {
        int d = ei[E + e];
        if ((unsigned)d < (unsigned)N) {
            int p = atomicAdd(&cursor[d], 1);
            ids[p] = e;
        }
    }
}

// ---------------------------- GEMMs ----------------------------
// h = x @ W1: x [N,11] fp32, W [11,1024] fp32 -> h [N,1024] bf16.
__global__ void gemm_k11(const float* __restrict__ x, const float* __restrict__ W,
                         unsigned short* __restrict__ h, int N) {
    int i = blockIdx.x * blockDim.x + threadIdx.x;
    if (i >= N * 1024) return;
    int n = i >> 10, j = i & 1023;
    float acc = 0.f;
#pragma unroll
    for (int k = 0; k < 11; k++) acc += x[n * 11 + k] * W[k * 1024 + j];
    h[i] = f2b(acc);
}

// W [K,N] fp32 -> Wt [N,K] bf16 (bf16-valued fp32 => lossless)
__global__ void transpose_w_kernel(const float* __restrict__ W,
                                   unsigned short* __restrict__ Wt, int K, int N) {
    int i = blockIdx.x * blockDim.x + threadIdx.x;
    if (i >= K * N) return;
    int k = i / N, n = i % N;
    Wt[(size_t)n * K + k] = f2b(W[i]);
}

// MFMA GEMM: C[M,N] = A[M,K] * Bt[N,K]^T. bf16 in, bf16 out, fp32 accum.
// Tiles: BM=128, BN=128, BK=32. 256 threads = 4 waves, each 64x64 quadrant.
// N%128==0, K%32==0. Fragment maps (gfx950, HW-verified per guide):
//   A: lane holds A[m=lane&15][k=quad*8+j]; B: B[k=quad*8+j][n=lane&15]
//   C/D: col=lane&15, row=quad*4+reg
__global__ __launch_bounds__(256) void gemm_mfma(
    const unsigned short* __restrict__ A, const unsigned short* __restrict__ Bt,
    unsigned short* __restrict__ C, int M, int N, int K) {
    __shared__ unsigned short As[128][40];  // [m][k], +8 pad
    __shared__ unsigned short Bs[128][40];  // [n][k], +8 pad
    int t = threadIdx.x;
    int w = t >> 6, lane = t & 63;
    int quad = lane >> 4, l16 = lane & 15;
    int bm = blockIdx.y * 128, bn = blockIdx.x * 128;
    int wr = (w >> 1) * 64, wc = (w & 1) * 64;
    f32x4 acc[4][4] = {};
    for (int k0 = 0; k0 < K; k0 += 32) {
#pragma unroll
        for (int rep = 0; rep < 2; rep++) {
            int linear = rep * 2048 + t * 8;
            int row = linear >> 5, col = linear & 31;
            int grow = bm + row;
            uint4 v = make_uint4(0, 0, 0, 0);
            if (grow < M) v = *(const uint4*)(A + (size_t)grow * K + k0 + col);
            *(uint4*)&As[row][col] = v;
            // Bt rows are output-cols; N%128==0 so always in-bounds
            uint4 bv = *(const uint4*)(Bt + (size_t)(bn + row) * K + k0 + col);
            *(uint4*)&Bs[row][col] = bv;
        }
        __syncthreads();
        short8 a[4], b[4];
#pragma unroll
        for (int mi = 0; mi < 4; mi++)
            a[mi] = *(const short8*)&As[wr + mi * 16 + l16][quad * 8];
#pragma unroll
        for (int ni = 0; ni < 4; ni++)
            b[ni] = *(const short8*)&Bs[wc + ni * 16 + l16][quad * 8];
#pragma unroll
        for (int mi = 0; mi < 4; mi++)
#pragma unroll
            for (int ni = 0; ni < 4; ni++)
                acc[mi][ni] = __builtin_amdgcn_mfma_f32_16x16x32_bf16(
                    a[mi], b[ni], acc[mi][ni], 0, 0, 0);
        __syncthreads();
    }
#pragma unroll
    for (int mi = 0; mi < 4; mi++) {
#pragma unroll
        for (int r = 0; r < 4; r++) {
            int row = bm + wr + mi * 16 + quad * 4 + r;
            if (row < M) {
#pragma unroll
                for (int ni = 0; ni < 4; ni++) {
                    int col = bn + wc + ni * 16 + l16;
                    C[(size_t)row * N + col] = f2b(acc[mi][ni][r]);
                }
            }
        }
    }
}

// ---------------------------- attention logits ----------------------------
__global__ void al_kernel(const unsigned short* __restrict__ h,
                          const float* __restrict__ a_s,
                          const float* __restrict__ a_d, float* __restrict__ als,
                          float* __restrict__ ald, int NH, int H, int C) {
    int wave = (int)((blockIdx.x * blockDim.x + threadIdx.x) >> 6);
    int lane = threadIdx.x & 63;
    if (wave >= NH) return;
    int n = wave / H, hh = wave % H;
    const unsigned short* hp = h + (size_t)n * H * C + (size_t)hh * C;
    const float* as = a_s + hh * C;
    const float* ad = a_d + hh * C;
    float s = 0.f, d = 0.f;
    for (int c = lane; c < C; c += 64) {
        float v = b2f(hp[c]);
        s += v * as[c];
        d += v * ad[c];
    }
    for (int o = 32; o; o >>= 1) {
        s += __shfl_xor(s, o);
        d += __shfl_xor(d, o);
    }
    if (lane == 0) { als[wave] = s; ald[wave] = d; }
}

// ---------------------- softmax: per-(n,h) max & inv-denominator ----------------------
template <int H>
__global__ void mden_kernel(const float* __restrict__ als,
                            const float* __restrict__ ald,
                            const int* __restrict__ rowst,
                            const int* __restrict__ ids,
                            const int* __restrict__ ei, float* __restrict__ mv,
                            float* __restrict__ dinv, int E, int N) {
    int i = blockIdx.x * blockDim.x + threadIdx.x;
    if (i >= N * H) return;
    int n = i / H, h = i % H;
    float aldn = ald[i];
    int start = rowst[n], end = rowst[n + 1];
    float v0 = als[n * H + h] + aldn;  // self-loop logit (always present)
    float m = v0 > 0.f ? v0 : 0.2f * v0;
    for (int idx = start; idx < end; ++idx) {
        int e = ids[idx];
        int s = (e < E) ? ei[e] : n;
        if ((unsigned)s >= (unsigned)N) s = n;
        float v = als[s * H + h] + aldn;
        v = v > 0.f ? v : 0.2f * v;
        m = fmaxf(m, v);
    }
    float den = 0.f;
    for (int idx = start; idx < end; ++idx) {
        int e = ids[idx];
        int s = (e < E) ? ei[e] : n;
        if ((unsigned)s >= (unsigned)N) s = n;
        float v = als[s * H + h] + aldn;
        v = v > 0.f ? v : 0.2f * v;
        den += expf(v - m);
    }
    mv[i] = m;
    dinv[i] = 1.0f / (den + EPS);
}

// ---------------------- per-(edge,head) alpha ----------------------
template <int H>
__global__ void alpha_kernel(const int* __restrict__ ei,
                             const float* __restrict__ als,
                             const float* __restrict__ ald,
                             const float* __restrict__ mv,
                             const float* __restrict__ dinv,
                             float* __restrict__ escr, int E, int N) {
    int i = blockIdx.x * blockDim.x + threadIdx.x;
    if (i >= (E + N) * H) return;
    int e = i / H, h = i % H;
    int s, d;
    if (e < E) {
        s = ei[e];
        d = ei[E + e];
        if ((unsigned)d >= (unsigned)N) { escr[i] = 0.f; return; }
        if ((unsigned)s >= (unsigned)N) s = d;
    } else {
        s = d = e - E;
    }
    float v = als[s * H + h] + ald[d * H + h];
    v = v > 0.f ? v : 0.2f * v;
    escr[i] = expf(v - mv[d * H + h]) * dinv[d * H + h];
}

// ---------------------- single-pass aggregation ----------------------
// block per dst node; ushort2 channel pairs; alpha read from escr.
template <int H, int C, int TPB>
__global__ void agg_kernel(const unsigned short* __restrict__ hin,
                           const float* __restrict__ escr,
                           const int* __restrict__ rowst,
                           const int* __restrict__ ids,
                           const int* __restrict__ ei,
                           const float* __restrict__ bias,
                           unsigned short* __restrict__ out, int E, int N) {
    constexpr int HC = H * C;
    constexpr int PER2 = HC / (2 * TPB);  // ushort2 groups per thread
    int n = blockIdx.x;
    int t = threadIdx.x;
    int start = rowst[n], end = rowst[n + 1];
    int myh[PER2];
    float acc0[PER2], acc1[PER2];
#pragma unroll
    for (int j = 0; j < PER2; j++) {
        myh[j] = (t * 2 + j * TPB * 2) / C;
        acc0[j] = 0.f;
        acc1[j] = 0.f;
    }
    for (int idx = start; idx < end; ++idx) {
        int e = ids[idx];
        int s = (e < E) ? ei[e] : n;
        if ((unsigned)s >= (unsigned)N) s = n;
        const unsigned short* hp = hin + (size_t)s * HC;
        const float* ep = escr + (size_t)e * H;
#pragma unroll
        for (int j = 0; j < PER2; j++) {
            int c = t * 2 + j * TPB * 2;
            float a = ep[myh[j]];
            ushort2 u = *(const ushort2*)&hp[c];
            acc0[j] += a * b2f(u.x);
            acc1[j] += a * b2f(u.y);
        }
    }
#pragma unroll
    for (int j = 0; j < PER2; j++) {
        int c = t * 2 + j * TPB * 2;
        float v0 = acc0[j] + bias[c];
        float v1 = acc1[j] + bias[c + 1];
        ushort2 o;
        o.x = f2b(v0 > 0.f ? v0 : 0.01f * v0);
        o.y = f2b(v1 > 0.f ? v1 : 0.01f * v1);
        *(ushort2*)&out[(size_t)n * HC + c] = o;
    }
}

// ---------------------- fused mean-pool + output head ----------------------
// batch is sorted; block g binary-searches its node range, sums 128 channels,
// then dot with Wout. 64 blocks x 128 threads.
__global__ void pool_head_kernel(const unsigned short* __restrict__ h3,
                                 const int* __restrict__ batch,
                                 const float* __restrict__ Wout,
                                 const float* __restrict__ bout,
                                 float* __restrict__ out, int N) {
    int g = blockIdx.x;
    int t = threadIdx.x;  // 128
    int lo, hi;
    {
        int a = 0, b = N;
        while (a < b) { int mid = (a + b) >> 1; if (batch[mid] < g) a = mid + 1; else b = mid; }
        lo = a;
        a = lo; b = N;
        while (a < b) { int mid = (a + b) >> 1; if (batch[mid] < g + 1) a = mid + 1; else b = mid; }
        hi = a;
    }
    float s = 0.f;
    for (int n = lo; n < hi; n++) s += b2f(h3[(size_t)n * 128 + t]);
    float c = (float)(hi - lo);
    c = c > 1.f ? c : 1.f;
    float v = (s / c) * Wout[t];
    for (int o = 32; o; o >>= 1) v += __shfl_xor(v, o);
    __shared__ float partial[2];
    if ((t & 63) == 0) partial[t >> 6] = v;
    __syncthreads();
    if (t == 0) out[g] = partial[0] + partial[1] + bout[0];
}

// ---------------------------- host orchestration ----------------------------
extern "C" void kernel_launch(void* const* d_in, const int* in_sizes, int n_in,
                              void* d_out, int out_size, void* d_ws,
                              size_t ws_size, hipStream_t stream) {
    const float* x = (const float*)d_in[0];
    const int* ei = (const int*)d_in[1];
    const int* batch = (const int*)d_in[2];
    const float* W1 = (const float*)d_in[3];
    const float* a1s = (const float*)d_in[4];
    const float* a1d = (const float*)d_in[5];
    const float* b1 = (const float*)d_in[6];
    const float* W2 = (const float*)d_in[7];
    const float* a2s = (const float*)d_in[8];
    const float* a2d = (const float*)d_in[9];
    const float* b2 = (const float*)d_in[10];
    const float* W3 = (const float*)d_in[11];
    const float* a3s = (const float*)d_in[12];
    const float* a3d = (const float*)d_in[13];
    const float* b3 = (const float*)d_in[14];
    const float* Wout = (const float*)d_in[15];
    const float* bout = (const float*)d_in[16];
    float* out = (float*)d_out;

    const int N = in_sizes[0] / 11;
    const int E = in_sizes[1] / 2;
    const int Etot = E + N;
    const int G = out_size;

    char* ws = (char*)d_ws;
    size_t off = 0;
    auto alloc = [&](size_t bytes) -> void* {
        void* p = ws + off;
        off += (bytes + 255) & ~(size_t)255;
        return p;
    };
    unsigned short* buf1 = (unsigned short*)alloc((size_t)N * 1024 * 2);  // h
    unsigned short* buf2 = (unsigned short*)alloc((size_t)N * 1024 * 2);  // out
    float* als = (float*)alloc((size_t)N * 8 * 4);
    float* ald = (float*)alloc((size_t)N * 8 * 4);
    float* mv = (float*)alloc((size_t)N * 8 * 4);
    float* dinv = (float*)alloc((size_t)N * 8 * 4);
    float* escr = (float*)alloc((size_t)Etot * 8 * 4);
    int* rowst = (int*)alloc((size_t)(N + 1) * 4);
    int* cursor = (int*)alloc((size_t)N * 4);
    int* ids = (int*)alloc((size_t)Etot * 4);
    int* deg = (int*)alloc((size_t)N * 4);
    unsigned short* wt2 = (unsigned short*)alloc((size_t)1024 * 512 * 2);
    unsigned short* wt3 = (unsigned short*)alloc((size_t)512 * 128 * 2);

    int nb = (N + 255) / 256;
    int eb = (E + 255) / 256;

    // ---- CSR by dst (self-loop id = E+n at row head) ----
    init_deg_kernel<<<nb, 256, 0, stream>>>(deg, N);
    hist_kernel<<<eb, 256, 0, stream>>>(ei, E, N, deg);
    scan_kernel<<<1, 64, 0, stream>>>(deg, rowst, N);
    selfloop_kernel<<<nb, 256, 0, stream>>>(rowst, ids, cursor, N, E);
    scatter_kernel<<<eb, 256, 0, stream>>>(ei, E, N, cursor, ids);

    // ---- weight transposes (bf16-valued fp32 -> bf16 [N,K]) ----
    transpose_w_kernel<<<(1024 * 512 + 255) / 256, 256, 0, stream>>>(W2, wt2,
                                                                     1024, 512);
    transpose_w_kernel<<<(512 * 128 + 255) / 256, 256, 0, stream>>>(W3, wt3,
                                                                    512, 128);

    // ---- Layer 1: x [N,11] -> h1=buf1 [N,1024]; H=8,C=128 -> out1=buf2 ----
    gemm_k11<<<(N * 1024 + 255) / 256, 256, 0, stream>>>(x, W1, buf1, N);
    al_kernel<<<(N * 8 + 3) / 4, 256, 0, stream>>>(buf1, a1s, a1d, als, ald,
                                                   N * 8, 8, 128);
    mden_kernel<8><<<(N * 8 + 255) / 256, 256, 0, stream>>>(als, ald, rowst, ids,
                                                            ei, mv, dinv, E, N);
    alpha_kernel<8><<<(Etot * 8 + 255) / 256, 256, 0, stream>>>(ei, als, ald, mv,
                                                                dinv, escr, E, N);
    agg_kernel<8, 128, 256><<<N, 256, 0, stream>>>(buf1, escr, rowst, ids, ei,
                                                   b1, buf2, E, N);

    // ---- Layer 2: out1 [N,1024] @ W2 -> h2=buf1 [N,512]; H=8,C=64 ----
    gemm_mfma<<<dim3(512 / 128, (N + 127) / 128), 256, 0, stream>>>(
        buf2, wt2, buf1, N, 512, 1024);
    al_kernel<<<(N * 8 + 3) / 4, 256, 0, stream>>>(buf1, a2s, a2d, als, ald,
                                                   N * 8, 8, 64);
    mden_kernel<8><<<(N * 8 + 255) / 256, 256, 0, stream>>>(als, ald, rowst, ids,
                                                            ei, mv, dinv, E, N);
    alpha_kernel<8><<<(Etot * 8 + 255) / 256, 256, 0, stream>>>(ei, als, ald, mv,
                                                                dinv, escr, E, N);
    agg_kernel<8, 64, 256><<<N, 256, 0, stream>>>(buf1, escr, rowst, ids, ei,
                                                  b2, buf2, E, N);

    // ---- Layer 3: out2 [N,512] @ W3 -> h3=buf1 [N,128]; H=4,C=32 ----
    gemm_mfma<<<dim3(128 / 128, (N + 127) / 128), 256, 0, stream>>>(
        buf2, wt3, buf1, N, 128, 512);
    al_kernel<<<(N * 4 + 3) / 4, 256, 0, stream>>>(buf1, a3s, a3d, als, ald,
                                                   N * 4, 4, 32);
    mden_kernel<4><<<(N * 4 + 255) / 256, 256, 0, stream>>>(als, ald, rowst, ids,
                                                            ei, mv, dinv, E, N);
    alpha_kernel<4><<<(Etot * 4 + 255) / 256, 256, 0, stream>>>(ei, als, ald, mv,
                                                                dinv, escr, E, N);
    agg_kernel<4, 32, 64><<<N, 64, 0, stream>>>(buf1, escr, rowst, ids, ei,
                                                b3, buf2, E, N);

    // ---- fused mean-pool + head ----
    pool_head_kernel<<<G, 128, 0, stream>>>(buf2, batch, Wout, bout, out, N);
}

// Round 7
// 1126.077 us; speedup vs baseline: 2.2691x; 1.2103x over previous
//
#include <hip/hip_runtime.h>

#define EPS 1e-16f

typedef __attribute__((ext_vector_type(8))) short short8;
typedef __attribute__((ext_vector_type(4))) float f32x4;

// ---------- bf16 <-> fp32 (internal storage only) ----------
__device__ __forceinline__ float b2f(unsigned short u) {
    return __uint_as_float(((unsigned)u) << 16);
}
__device__ __forceinline__ unsigned short f2b(float f) {
    unsigned u = __float_as_uint(f);
    u += 0x7fffu + ((u >> 16) & 1u);  // round-to-nearest-even
    return (unsigned short)(u >> 16);
}

// ---------------------------- CSR build ----------------------------
__global__ void init_deg_kernel(int* deg, int N) {
    int i = blockIdx.x * blockDim.x + threadIdx.x;
    if (i < N) deg[i] = 1;  // self-loop
}

__global__ void hist_kernel(const int* __restrict__ ei, int E, int N, int* deg) {
    int e = blockIdx.x * blockDim.x + threadIdx.x;
    if (e < E) {
        int d = ei[E + e];
        if ((unsigned)d < (unsigned)N) atomicAdd(&deg[d], 1);
    }
}

// phase 1: per-block inclusive scan of 256 elems -> rowst[i+1]; total -> bsum[b]
__global__ void scan_block_kernel(const int* __restrict__ deg,
                                  int* __restrict__ rowst,
                                  int* __restrict__ bsum, int N) {
    __shared__ int s[256];
    int t = threadIdx.x, b = blockIdx.x;
    int i = b * 256 + t;
    s[t] = (i < N) ? deg[i] : 0;
    __syncthreads();
    for (int o = 1; o < 256; o <<= 1) {
        int a = (t >= o) ? s[t - o] : 0;
        __syncthreads();
        s[t] += a;
        __syncthreads();
    }
    if (i < N) rowst[i + 1] = s[t];
    if (t == 255) bsum[b] = s[255];
}

// phase 2: one wave exclusive-scans bsum[NB] in place -> boff
__global__ void scan_top_kernel(const int* __restrict__ bsum,
                                int* __restrict__ boff, int NB) {
    __shared__ int psum[65];
    int t = threadIdx.x;  // 64
    int chunk = (NB + 63) / 64;
    int lo = t * chunk, hi = lo + chunk;
    if (lo > NB) lo = NB;
    if (hi > NB) hi = NB;
    int s = 0;
    for (int i = lo; i < hi; i++) s += bsum[i];
    psum[t + 1] = s;
    __syncthreads();
    if (t == 0) {
        psum[0] = 0;
        for (int i = 1; i <= 64; i++) psum[i] += psum[i - 1];
    }
    __syncthreads();
    int run = psum[t];
    for (int i = lo; i < hi; i++) {
        boff[i] = run;  // exclusive
        run += bsum[i];
    }
}

// phase 3: add block offsets; set rowst[0]=0
__global__ void scan_add_kernel(int* __restrict__ rowst,
                                const int* __restrict__ boff, int N) {
    int i = blockIdx.x * 256 + threadIdx.x;
    if (i == 0) rowst[0] = 0;
    if (i < N) rowst[i + 1] += boff[blockIdx.x];
}

__global__ void selfloop_kernel(const int* __restrict__ rowst, int* ids,
                                int* cursor, int N, int E) {
    int n = blockIdx.x * blockDim.x + threadIdx.x;
    if (n < N) {
        ids[rowst[n]] = E + n;  // self-loop edge id
        cursor[n] = rowst[n] + 1;
    }
}

__global__ void scatter_kernel(const int* __restrict__ ei, int E, int N,
                               int* cursor, int* ids) {
    int e = blockIdx.x * blockDim.x + threadIdx.x;
    if (e < E) {
        int d = ei[E + e];
        if ((unsigned)d < (unsigned)N) {
            int p = atomicAdd(&cursor[d], 1);
            ids[p] = e;
        }
    }
}

// ---------------------------- GEMMs ----------------------------
// h = x @ W1: x [N,11] fp32, W [11,1024] fp32 -> h [N,1024] bf16.
__global__ void gemm_k11(const float* __restrict__ x, const float* __restrict__ W,
                         unsigned short* __restrict__ h, int N) {
    int i = blockIdx.x * blockDim.x + threadIdx.x;
    if (i >= N * 1024) return;
    int n = i >> 10, j = i & 1023;
    float acc = 0.f;
#pragma unroll
    for (int k = 0; k < 11; k++) acc += x[n * 11 + k] * W[k * 1024 + j];
    h[i] = f2b(acc);
}

// W [K,N] fp32 -> Wt [N,K] bf16 (bf16-valued fp32 => lossless)
__global__ void transpose_w_kernel(const float* __restrict__ W,
                                   unsigned short* __restrict__ Wt, int K, int N) {
    int i = blockIdx.x * blockDim.x + threadIdx.x;
    if (i >= K * N) return;
    int k = i / N, n = i % N;
    Wt[(size_t)n * K + k] = f2b(W[i]);
}

// MFMA GEMM: C[M,N] = A[M,K] * Bt[N,K]^T. bf16 in/out, fp32 accum.
// BM=BN=128, BK=32; 4 waves each own a 64x64 quadrant.
__global__ __launch_bounds__(256) void gemm_mfma(
    const unsigned short* __restrict__ A, const unsigned short* __restrict__ Bt,
    unsigned short* __restrict__ C, int M, int N, int K) {
    __shared__ unsigned short As[128][40];  // [m][k], +8 pad
    __shared__ unsigned short Bs[128][40];  // [n][k], +8 pad
    int t = threadIdx.x;
    int w = t >> 6, lane = t & 63;
    int quad = lane >> 4, l16 = lane & 15;
    int bm = blockIdx.y * 128, bn = blockIdx.x * 128;
    int wr = (w >> 1) * 64, wc = (w & 1) * 64;
    f32x4 acc[4][4] = {};
    for (int k0 = 0; k0 < K; k0 += 32) {
#pragma unroll
        for (int rep = 0; rep < 2; rep++) {
            int linear = rep * 2048 + t * 8;
            int row = linear >> 5, col = linear & 31;
            int grow = bm + row;
            uint4 v = make_uint4(0, 0, 0, 0);
            if (grow < M) v = *(const uint4*)(A + (size_t)grow * K + k0 + col);
            *(uint4*)&As[row][col] = v;
            uint4 bv = *(const uint4*)(Bt + (size_t)(bn + row) * K + k0 + col);
            *(uint4*)&Bs[row][col] = bv;
        }
        __syncthreads();
        short8 a[4], b[4];
#pragma unroll
        for (int mi = 0; mi < 4; mi++)
            a[mi] = *(const short8*)&As[wr + mi * 16 + l16][quad * 8];
#pragma unroll
        for (int ni = 0; ni < 4; ni++)
            b[ni] = *(const short8*)&Bs[wc + ni * 16 + l16][quad * 8];
#pragma unroll
        for (int mi = 0; mi < 4; mi++)
#pragma unroll
            for (int ni = 0; ni < 4; ni++)
                acc[mi][ni] = __builtin_amdgcn_mfma_f32_16x16x32_bf16(
                    a[mi], b[ni], acc[mi][ni], 0, 0, 0);
        __syncthreads();
    }
#pragma unroll
    for (int mi = 0; mi < 4; mi++) {
#pragma unroll
        for (int r = 0; r < 4; r++) {
            int row = bm + wr + mi * 16 + quad * 4 + r;
            if (row < M) {
#pragma unroll
                for (int ni = 0; ni < 4; ni++) {
                    int col = bn + wc + ni * 16 + l16;
                    C[(size_t)row * N + col] = f2b(acc[mi][ni][r]);
                }
            }
        }
    }
}

// ---------------------------- attention logits ----------------------------
__global__ void al_kernel(const unsigned short* __restrict__ h,
                          const float* __restrict__ a_s,
                          const float* __restrict__ a_d, float* __restrict__ als,
                          float* __restrict__ ald, int NH, int H, int C) {
    int wave = (int)((blockIdx.x * blockDim.x + threadIdx.x) >> 6);
    int lane = threadIdx.x & 63;
    if (wave >= NH) return;
    int n = wave / H, hh = wave % H;
    const unsigned short* hp = h + (size_t)n * H * C + (size_t)hh * C;
    const float* as = a_s + hh * C;
    const float* ad = a_d + hh * C;
    float s = 0.f, d = 0.f;
    for (int c = lane; c < C; c += 64) {
        float v = b2f(hp[c]);
        s += v * as[c];
        d += v * ad[c];
    }
    for (int o = 32; o; o >>= 1) {
        s += __shfl_xor(s, o);
        d += __shfl_xor(d, o);
    }
    if (lane == 0) { als[wave] = s; ald[wave] = d; }
}

// ---------------- softmax: per-(n,h) max & inv-denominator ----------------
template <int H>
__global__ void mden_kernel(const float* __restrict__ als,
                            const float* __restrict__ ald,
                            const int* __restrict__ rowst,
                            const int* __restrict__ ids,
                            const int* __restrict__ ei, float* __restrict__ mv,
                            float* __restrict__ dinv, int E, int N) {
    int i = blockIdx.x * blockDim.x + threadIdx.x;
    if (i >= N * H) return;
    int n = i / H, h = i % H;
    float aldn = ald[i];
    int start = rowst[n], end = rowst[n + 1];
    float v0 = als[n * H + h] + aldn;  // self-loop logit (always present)
    float m = v0 > 0.f ? v0 : 0.2f * v0;
    for (int idx = start; idx < end; ++idx) {
        int e = ids[idx];
        int s = (e < E) ? ei[e] : n;
        if ((unsigned)s >= (unsigned)N) s = n;
        float v = als[s * H + h] + aldn;
        v = v > 0.f ? v : 0.2f * v;
        m = fmaxf(m, v);
    }
    float den = 0.f;
    for (int idx = start; idx < end; ++idx) {
        int e = ids[idx];
        int s = (e < E) ? ei[e] : n;
        if ((unsigned)s >= (unsigned)N) s = n;
        float v = als[s * H + h] + aldn;
        v = v > 0.f ? v : 0.2f * v;
        den += expf(v - m);
    }
    mv[i] = m;
    dinv[i] = 1.0f / (den + EPS);
}

// ---------------------- per-(edge,head) alpha ----------------------
template <int H>
__global__ void alpha_kernel(const int* __restrict__ ei,
                             const float* __restrict__ als,
                             const float* __restrict__ ald,
                             const float* __restrict__ mv,
                             const float* __restrict__ dinv,
                             float* __restrict__ escr, int E, int N) {
    int i = blockIdx.x * blockDim.x + threadIdx.x;
    if (i >= (E + N) * H) return;
    int e = i / H, h = i % H;
    int s, d;
    if (e < E) {
        s = ei[e];
        d = ei[E + e];
        if ((unsigned)d >= (unsigned)N) { escr[i] = 0.f; return; }
        if ((unsigned)s >= (unsigned)N) s = d;
    } else {
        s = d = e - E;
    }
    float v = als[s * H + h] + ald[d * H + h];
    v = v > 0.f ? v : 0.2f * v;
    escr[i] = expf(v - mv[d * H + h]) * dinv[d * H + h];
}

// ---------------------- single-pass aggregation ----------------------
template <int H, int C, int TPB>
__global__ void agg_kernel(const unsigned short* __restrict__ hin,
                           const float* __restrict__ escr,
                           const int* __restrict__ rowst,
                           const int* __restrict__ ids,
                           const int* __restrict__ ei,
                           const float* __restrict__ bias,
                           unsigned short* __restrict__ out, int E, int N) {
    constexpr int HC = H * C;
    constexpr int PER2 = HC / (2 * TPB);  // ushort2 groups per thread
    int n = blockIdx.x;
    int t = threadIdx.x;
    int start = rowst[n], end = rowst[n + 1];
    int myh[PER2];
    float acc0[PER2], acc1[PER2];
#pragma unroll
    for (int j = 0; j < PER2; j++) {
        myh[j] = (t * 2 + j * TPB * 2) / C;
        acc0[j] = 0.f;
        acc1[j] = 0.f;
    }
    for (int idx = start; idx < end; ++idx) {
        int e = ids[idx];
        int s = (e < E) ? ei[e] : n;
        if ((unsigned)s >= (unsigned)N) s = n;
        const unsigned short* hp = hin + (size_t)s * HC;
        const float* ep = escr + (size_t)e * H;
#pragma unroll
        for (int j = 0; j < PER2; j++) {
            int c = t * 2 + j * TPB * 2;
            float a = ep[myh[j]];
            ushort2 u = *(const ushort2*)&hp[c];
            acc0[j] += a * b2f(u.x);
            acc1[j] += a * b2f(u.y);
        }
    }
#pragma unroll
    for (int j = 0; j < PER2; j++) {
        int c = t * 2 + j * TPB * 2;
        float v0 = acc0[j] + bias[c];
        float v1 = acc1[j] + bias[c + 1];
        ushort2 o;
        o.x = f2b(v0 > 0.f ? v0 : 0.01f * v0);
        o.y = f2b(v1 > 0.f ? v1 : 0.01f * v1);
        *(ushort2*)&out[(size_t)n * HC + c] = o;
    }
}

// ---------------------- fused mean-pool + output head ----------------------
__global__ void pool_head_kernel(const unsigned short* __restrict__ h3,
                                 const int* __restrict__ batch,
                                 const float* __restrict__ Wout,
                                 const float* __restrict__ bout,
                                 float* __restrict__ out, int N) {
    int g = blockIdx.x;
    int t = threadIdx.x;  // 128
    int lo, hi;
    {
        int a = 0, b = N;
        while (a < b) { int mid = (a + b) >> 1; if (batch[mid] < g) a = mid + 1; else b = mid; }
        lo = a;
        a = lo; b = N;
        while (a < b) { int mid = (a + b) >> 1; if (batch[mid] < g + 1) a = mid + 1; else b = mid; }
        hi = a;
    }
    float s = 0.f;
    for (int n = lo; n < hi; n++) s += b2f(h3[(size_t)n * 128 + t]);
    float c = (float)(hi - lo);
    c = c > 1.f ? c : 1.f;
    float v = (s / c) * Wout[t];
    for (int o = 32; o; o >>= 1) v += __shfl_xor(v, o);
    __shared__ float partial[2];
    if ((t & 63) == 0) partial[t >> 6] = v;
    __syncthreads();
    if (t == 0) out[g] = partial[0] + partial[1] + bout[0];
}

// ---------------------------- host orchestration ----------------------------
extern "C" void kernel_launch(void* const* d_in, const int* in_sizes, int n_in,
                              void* d_out, int out_size, void* d_ws,
                              size_t ws_size, hipStream_t stream) {
    const float* x = (const float*)d_in[0];
    const int* ei = (const int*)d_in[1];
    const int* batch = (const int*)d_in[2];
    const float* W1 = (const float*)d_in[3];
    const float* a1s = (const float*)d_in[4];
    const float* a1d = (const float*)d_in[5];
    const float* b1 = (const float*)d_in[6];
    const float* W2 = (const float*)d_in[7];
    const float* a2s = (const float*)d_in[8];
    const float* a2d = (const float*)d_in[9];
    const float* b2 = (const float*)d_in[10];
    const float* W3 = (const float*)d_in[11];
    const float* a3s = (const float*)d_in[12];
    const float* a3d = (const float*)d_in[13];
    const float* b3 = (const float*)d_in[14];
    const float* Wout = (const float*)d_in[15];
    const float* bout = (const float*)d_in[16];
    float* out = (float*)d_out;

    const int N = in_sizes[0] / 11;
    const int E = in_sizes[1] / 2;
    const int Etot = E + N;
    const int G = out_size;
    const int NB = (N + 255) / 256;  // scan blocks

    char* ws = (char*)d_ws;
    size_t off = 0;
    auto alloc = [&](size_t bytes) -> void* {
        void* p = ws + off;
        off += (bytes + 255) & ~(size_t)255;
        return p;
    };
    unsigned short* buf1 = (unsigned short*)alloc((size_t)N * 1024 * 2);  // h
    unsigned short* buf2 = (unsigned short*)alloc((size_t)N * 1024 * 2);  // out
    float* als = (float*)alloc((size_t)N * 8 * 4);
    float* ald = (float*)alloc((size_t)N * 8 * 4);
    float* mv = (float*)alloc((size_t)N * 8 * 4);
    float* dinv = (float*)alloc((size_t)N * 8 * 4);
    float* escr = (float*)alloc((size_t)Etot * 8 * 4);
    int* rowst = (int*)alloc((size_t)(N + 1) * 4);
    int* cursor = (int*)alloc((size_t)N * 4);
    int* ids = (int*)alloc((size_t)Etot * 4);
    int* deg = (int*)alloc((size_t)N * 4);
    int* bsum = (int*)alloc((size_t)NB * 4);
    int* boff = (int*)alloc((size_t)NB * 4);
    unsigned short* wt2 = (unsigned short*)alloc((size_t)1024 * 512 * 2);
    unsigned short* wt3 = (unsigned short*)alloc((size_t)512 * 128 * 2);

    int nb = (N + 255) / 256;
    int eb = (E + 255) / 256;

    // ---- CSR by dst (self-loop id = E+n at row head) ----
    init_deg_kernel<<<nb, 256, 0, stream>>>(deg, N);
    hist_kernel<<<eb, 256, 0, stream>>>(ei, E, N, deg);
    scan_block_kernel<<<NB, 256, 0, stream>>>(deg, rowst, bsum, N);
    scan_top_kernel<<<1, 64, 0, stream>>>(bsum, boff, NB);
    scan_add_kernel<<<NB, 256, 0, stream>>>(rowst, boff, N);
    selfloop_kernel<<<nb, 256, 0, stream>>>(rowst, ids, cursor, N, E);
    scatter_kernel<<<eb, 256, 0, stream>>>(ei, E, N, cursor, ids);

    // ---- weight transposes (bf16-valued fp32 -> bf16 [N,K]) ----
    transpose_w_kernel<<<(1024 * 512 + 255) / 256, 256, 0, stream>>>(W2, wt2,
                                                                     1024, 512);
    transpose_w_kernel<<<(512 * 128 + 255) / 256, 256, 0, stream>>>(W3, wt3,
                                                                    512, 128);

    // ---- Layer 1: x [N,11] -> h1=buf1 [N,1024]; H=8,C=128 -> out1=buf2 ----
    gemm_k11<<<(N * 1024 + 255) / 256, 256, 0, stream>>>(x, W1, buf1, N);
    al_kernel<<<(N * 8 + 3) / 4, 256, 0, stream>>>(buf1, a1s, a1d, als, ald,
                                                   N * 8, 8, 128);
    mden_kernel<8><<<(N * 8 + 255) / 256, 256, 0, stream>>>(als, ald, rowst, ids,
                                                            ei, mv, dinv, E, N);
    alpha_kernel<8><<<(Etot * 8 + 255) / 256, 256, 0, stream>>>(ei, als, ald, mv,
                                                                dinv, escr, E, N);
    agg_kernel<8, 128, 256><<<N, 256, 0, stream>>>(buf1, escr, rowst, ids, ei,
                                                   b1, buf2, E, N);

    // ---- Layer 2: out1 [N,1024] @ W2 -> h2=buf1 [N,512]; H=8,C=64 ----
    gemm_mfma<<<dim3(512 / 128, (N + 127) / 128), 256, 0, stream>>>(
        buf2, wt2, buf1, N, 512, 1024);
    al_kernel<<<(N * 8 + 3) / 4, 256, 0, stream>>>(buf1, a2s, a2d, als, ald,
                                                   N * 8, 8, 64);
    mden_kernel<8><<<(N * 8 + 255) / 256, 256, 0, stream>>>(als, ald, rowst, ids,
                                                            ei, mv, dinv, E, N);
    alpha_kernel<8><<<(Etot * 8 + 255) / 256, 256, 0, stream>>>(ei, als, ald, mv,
                                                                dinv, escr, E, N);
    agg_kernel<8, 64, 256><<<N, 256, 0, stream>>>(buf1, escr, rowst, ids, ei,
                                                  b2, buf2, E, N);

    // ---- Layer 3: out2 [N,512] @ W3 -> h3=buf1 [N,128]; H=4,C=32 ----
    gemm_mfma<<<dim3(128 / 128, (N + 127) / 128), 256, 0, stream>>>(
        buf2, wt3, buf1, N, 128, 512);
    al_kernel<<<(N * 4 + 3) / 4, 256, 0, stream>>>(buf1, a3s, a3d, als, ald,
                                                   N * 4, 4, 32);
    mden_kernel<4><<<(N * 4 + 255) / 256, 256, 0, stream>>>(als, ald, rowst, ids,
                                                            ei, mv, dinv, E, N);
    alpha_kernel<4><<<(Etot * 4 + 255) / 256, 256, 0, stream>>>(ei, als, ald, mv,
                                                                dinv, escr, E, N);
    agg_kernel<4, 32, 64><<<N, 64, 0, stream>>>(buf1, escr, rowst, ids, ei,
                                                b3, buf2, E, N);

    // ---- fused mean-pool + head ----
    pool_head_kernel<<<G, 128, 0, stream>>>(buf2, batch, Wout, bout, out, N);
}

// Round 8
// 928.278 us; speedup vs baseline: 2.7526x; 1.2131x over previous
//
#include <hip/hip_runtime.h>

#define EPS 1e-16f

typedef __attribute__((ext_vector_type(8))) short short8;
typedef __attribute__((ext_vector_type(4))) float f32x4;

// ---------- bf16 <-> fp32 (internal storage only) ----------
__device__ __forceinline__ float b2f(unsigned short u) {
    return __uint_as_float(((unsigned)u) << 16);
}
__device__ __forceinline__ unsigned short f2b(float f) {
    unsigned u = __float_as_uint(f);
    u += 0x7fffu + ((u >> 16) & 1u);  // round-to-nearest-even
    return (unsigned short)(u >> 16);
}

// ---------------------------- CSR build ----------------------------
__global__ void init_deg_kernel(int* deg, int N) {
    int i = blockIdx.x * blockDim.x + threadIdx.x;
    if (i < N) deg[i] = 1;  // self-loop
}

__global__ void hist_kernel(const int* __restrict__ ei, int E, int N, int* deg) {
    int e = blockIdx.x * blockDim.x + threadIdx.x;
    if (e < E) {
        int d = ei[E + e];
        if ((unsigned)d < (unsigned)N) atomicAdd(&deg[d], 1);
    }
}

// phase 1: per-block inclusive scan of 256 elems -> rowst[i+1]; total -> bsum[b]
__global__ void scan_block_kernel(const int* __restrict__ deg,
                                  int* __restrict__ rowst,
                                  int* __restrict__ bsum, int N) {
    __shared__ int s[256];
    int t = threadIdx.x, b = blockIdx.x;
    int i = b * 256 + t;
    s[t] = (i < N) ? deg[i] : 0;
    __syncthreads();
    for (int o = 1; o < 256; o <<= 1) {
        int a = (t >= o) ? s[t - o] : 0;
        __syncthreads();
        s[t] += a;
        __syncthreads();
    }
    if (i < N) rowst[i + 1] = s[t];
    if (t == 255) bsum[b] = s[255];
}

// phase 2: one wave exclusive-scans bsum[NB] -> boff
__global__ void scan_top_kernel(const int* __restrict__ bsum,
                                int* __restrict__ boff, int NB) {
    __shared__ int psum[65];
    int t = threadIdx.x;  // 64
    int chunk = (NB + 63) / 64;
    int lo = t * chunk, hi = lo + chunk;
    if (lo > NB) lo = NB;
    if (hi > NB) hi = NB;
    int s = 0;
    for (int i = lo; i < hi; i++) s += bsum[i];
    psum[t + 1] = s;
    __syncthreads();
    if (t == 0) {
        psum[0] = 0;
        for (int i = 1; i <= 64; i++) psum[i] += psum[i - 1];
    }
    __syncthreads();
    int run = psum[t];
    for (int i = lo; i < hi; i++) {
        boff[i] = run;  // exclusive
        run += bsum[i];
    }
}

// phase 3: add block offsets; set rowst[0]=0
__global__ void scan_add_kernel(int* __restrict__ rowst,
                                const int* __restrict__ boff, int N) {
    int i = blockIdx.x * 256 + threadIdx.x;
    if (i == 0) rowst[0] = 0;
    if (i < N) rowst[i + 1] += boff[blockIdx.x];
}

__global__ void selfloop_kernel(const int* __restrict__ rowst, int* ids,
                                int* cursor, int N, int E) {
    int n = blockIdx.x * blockDim.x + threadIdx.x;
    if (n < N) {
        ids[rowst[n]] = E + n;  // self-loop edge id
        cursor[n] = rowst[n] + 1;
    }
}

__global__ void scatter_kernel(const int* __restrict__ ei, int E, int N,
                               int* cursor, int* ids) {
    int e = blockIdx.x * blockDim.x + threadIdx.x;
    if (e < E) {
        int d = ei[E + e];
        if ((unsigned)d < (unsigned)N) {
            int p = atomicAdd(&cursor[d], 1);
            ids[p] = e;
        }
    }
}

// ---------------------------- GEMMs ----------------------------
// h = x @ W1: x [N,11] fp32, W [11,1024] fp32 -> h [N,1024] bf16.
__global__ void gemm_k11(const float* __restrict__ x, const float* __restrict__ W,
                         unsigned short* __restrict__ h, int N) {
    int i = blockIdx.x * blockDim.x + threadIdx.x;
    if (i >= N * 1024) return;
    int n = i >> 10, j = i & 1023;
    float acc = 0.f;
#pragma unroll
    for (int k = 0; k < 11; k++) acc += x[n * 11 + k] * W[k * 1024 + j];
    h[i] = f2b(acc);
}

// W [K,N] fp32 -> Wt [N,K] bf16 (bf16-valued fp32 => lossless)
__global__ void transpose_w_kernel(const float* __restrict__ W,
                                   unsigned short* __restrict__ Wt, int K, int N) {
    int i = blockIdx.x * blockDim.x + threadIdx.x;
    if (i >= K * N) return;
    int k = i / N, n = i % N;
    Wt[(size_t)n * K + k] = f2b(W[i]);
}

// MFMA GEMM: C[M,N] = A[M,K] * Bt[N,K]^T. bf16 in/out, fp32 accum.
// BM=BN=128, BK=32; 4 waves each own a 64x64 quadrant.
__global__ __launch_bounds__(256) void gemm_mfma(
    const unsigned short* __restrict__ A, const unsigned short* __restrict__ Bt,
    unsigned short* __restrict__ C, int M, int N, int K) {
    __shared__ unsigned short As[128][40];  // [m][k], +8 pad
    __shared__ unsigned short Bs[128][40];  // [n][k], +8 pad
    int t = threadIdx.x;
    int w = t >> 6, lane = t & 63;
    int quad = lane >> 4, l16 = lane & 15;
    int bm = blockIdx.y * 128, bn = blockIdx.x * 128;
    int wr = (w >> 1) * 64, wc = (w & 1) * 64;
    f32x4 acc[4][4] = {};
    for (int k0 = 0; k0 < K; k0 += 32) {
#pragma unroll
        for (int rep = 0; rep < 2; rep++) {
            int linear = rep * 2048 + t * 8;
            int row = linear >> 5, col = linear & 31;
            int grow = bm + row;
            uint4 v = make_uint4(0, 0, 0, 0);
            if (grow < M) v = *(const uint4*)(A + (size_t)grow * K + k0 + col);
            *(uint4*)&As[row][col] = v;
            uint4 bv = *(const uint4*)(Bt + (size_t)(bn + row) * K + k0 + col);
            *(uint4*)&Bs[row][col] = bv;
        }
        __syncthreads();
        short8 a[4], b[4];
#pragma unroll
        for (int mi = 0; mi < 4; mi++)
            a[mi] = *(const short8*)&As[wr + mi * 16 + l16][quad * 8];
#pragma unroll
        for (int ni = 0; ni < 4; ni++)
            b[ni] = *(const short8*)&Bs[wc + ni * 16 + l16][quad * 8];
#pragma unroll
        for (int mi = 0; mi < 4; mi++)
#pragma unroll
            for (int ni = 0; ni < 4; ni++)
                acc[mi][ni] = __builtin_amdgcn_mfma_f32_16x16x32_bf16(
                    a[mi], b[ni], acc[mi][ni], 0, 0, 0);
        __syncthreads();
    }
#pragma unroll
    for (int mi = 0; mi < 4; mi++) {
#pragma unroll
        for (int r = 0; r < 4; r++) {
            int row = bm + wr + mi * 16 + quad * 4 + r;
            if (row < M) {
#pragma unroll
                for (int ni = 0; ni < 4; ni++) {
                    int col = bn + wc + ni * 16 + l16;
                    C[(size_t)row * N + col] = f2b(acc[mi][ni][r]);
                }
            }
        }
    }
}

// ---------------------------- attention logits ----------------------------
__global__ void al_kernel(const unsigned short* __restrict__ h,
                          const float* __restrict__ a_s,
                          const float* __restrict__ a_d, float* __restrict__ als,
                          float* __restrict__ ald, int NH, int H, int C) {
    int wave = (int)((blockIdx.x * blockDim.x + threadIdx.x) >> 6);
    int lane = threadIdx.x & 63;
    if (wave >= NH) return;
    int n = wave / H, hh = wave % H;
    const unsigned short* hp = h + (size_t)n * H * C + (size_t)hh * C;
    const float* as = a_s + hh * C;
    const float* ad = a_d + hh * C;
    float s = 0.f, d = 0.f;
    for (int c = lane; c < C; c += 64) {
        float v = b2f(hp[c]);
        s += v * as[c];
        d += v * ad[c];
    }
    for (int o = 32; o; o >>= 1) {
        s += __shfl_xor(s, o);
        d += __shfl_xor(d, o);
    }
    if (lane == 0) { als[wave] = s; ald[wave] = d; }
}

// ---------------- softmax: per-(n,h) max & inv-denominator ----------------
template <int H>
__global__ void mden_kernel(const float* __restrict__ als,
                            const float* __restrict__ ald,
                            const int* __restrict__ rowst,
                            const int* __restrict__ ids,
                            const int* __restrict__ ei, float* __restrict__ mv,
                            float* __restrict__ dinv, int E, int N) {
    int i = blockIdx.x * blockDim.x + threadIdx.x;
    if (i >= N * H) return;
    int n = i / H, h = i % H;
    float aldn = ald[i];
    int start = rowst[n], end = rowst[n + 1];
    float v0 = als[n * H + h] + aldn;  // self-loop logit (always present)
    float m = v0 > 0.f ? v0 : 0.2f * v0;
    for (int idx = start; idx < end; ++idx) {
        int e = ids[idx];
        int s = (e < E) ? ei[e] : n;
        if ((unsigned)s >= (unsigned)N) s = n;
        float v = als[s * H + h] + aldn;
        v = v > 0.f ? v : 0.2f * v;
        m = fmaxf(m, v);
    }
    float den = 0.f;
    for (int idx = start; idx < end; ++idx) {
        int e = ids[idx];
        int s = (e < E) ? ei[e] : n;
        if ((unsigned)s >= (unsigned)N) s = n;
        float v = als[s * H + h] + aldn;
        v = v > 0.f ? v : 0.2f * v;
        den += expf(v - m);
    }
    mv[i] = m;
    dinv[i] = 1.0f / (den + EPS);
}

// ---------------------- per-(edge,head) alpha ----------------------
template <int H>
__global__ void alpha_kernel(const int* __restrict__ ei,
                             const float* __restrict__ als,
                             const float* __restrict__ ald,
                             const float* __restrict__ mv,
                             const float* __restrict__ dinv,
                             float* __restrict__ escr, int E, int N) {
    int i = blockIdx.x * blockDim.x + threadIdx.x;
    if (i >= (E + N) * H) return;
    int e = i / H, h = i % H;
    int s, d;
    if (e < E) {
        s = ei[e];
        d = ei[E + e];
        if ((unsigned)d >= (unsigned)N) { escr[i] = 0.f; return; }
        if ((unsigned)s >= (unsigned)N) s = d;
    } else {
        s = d = e - E;
    }
    float v = als[s * H + h] + ald[d * H + h];
    v = v > 0.f ? v : 0.2f * v;
    escr[i] = expf(v - mv[d * H + h]) * dinv[d * H + h];
}

// ---------------------- single-pass aggregation, ushort4 ----------------------
// TPB = H*C/4; thread owns 4 contiguous channels (same head since C%4==0).
template <int H, int C>
__global__ void agg_kernel4(const unsigned short* __restrict__ hin,
                            const float* __restrict__ escr,
                            const int* __restrict__ rowst,
                            const int* __restrict__ ids,
                            const int* __restrict__ ei,
                            const float* __restrict__ bias,
                            unsigned short* __restrict__ out, int E, int N) {
    constexpr int HC = H * C;
    int n = blockIdx.x;
    int t = threadIdx.x;  // HC/4 threads
    int c = t * 4;
    int hh = c / C;
    int start = rowst[n], end = rowst[n + 1];
    float a0 = 0.f, a1 = 0.f, a2 = 0.f, a3 = 0.f;
    for (int idx = start; idx < end; ++idx) {
        int e = ids[idx];
        int s = (e < E) ? ei[e] : n;
        if ((unsigned)s >= (unsigned)N) s = n;
        float a = escr[(size_t)e * H + hh];
        ushort4 u = *(const ushort4*)(hin + (size_t)s * HC + c);
        a0 += a * b2f(u.x);
        a1 += a * b2f(u.y);
        a2 += a * b2f(u.z);
        a3 += a * b2f(u.w);
    }
    float v0 = a0 + bias[c], v1 = a1 + bias[c + 1];
    float v2 = a2 + bias[c + 2], v3 = a3 + bias[c + 3];
    ushort4 o;
    o.x = f2b(v0 > 0.f ? v0 : 0.01f * v0);
    o.y = f2b(v1 > 0.f ? v1 : 0.01f * v1);
    o.z = f2b(v2 > 0.f ? v2 : 0.01f * v2);
    o.w = f2b(v3 > 0.f ? v3 : 0.01f * v3);
    *(ushort4*)&out[(size_t)n * HC + c] = o;
}

// ushort2 variant for small HC (layer 3: HC=128, TPB=64)
template <int H, int C, int TPB>
__global__ void agg_kernel2(const unsigned short* __restrict__ hin,
                            const float* __restrict__ escr,
                            const int* __restrict__ rowst,
                            const int* __restrict__ ids,
                            const int* __restrict__ ei,
                            const float* __restrict__ bias,
                            unsigned short* __restrict__ out, int E, int N) {
    constexpr int HC = H * C;
    int n = blockIdx.x;
    int t = threadIdx.x;
    int c = t * 2;
    int hh = c / C;
    int start = rowst[n], end = rowst[n + 1];
    float a0 = 0.f, a1 = 0.f;
    for (int idx = start; idx < end; ++idx) {
        int e = ids[idx];
        int s = (e < E) ? ei[e] : n;
        if ((unsigned)s >= (unsigned)N) s = n;
        float a = escr[(size_t)e * H + hh];
        ushort2 u = *(const ushort2*)(hin + (size_t)s * HC + c);
        a0 += a * b2f(u.x);
        a1 += a * b2f(u.y);
    }
    float v0 = a0 + bias[c], v1 = a1 + bias[c + 1];
    ushort2 o;
    o.x = f2b(v0 > 0.f ? v0 : 0.01f * v0);
    o.y = f2b(v1 > 0.f ? v1 : 0.01f * v1);
    *(ushort2*)&out[(size_t)n * HC + c] = o;
}

// ---------------------- parallel mean-pool + head ----------------------
__global__ void pool_init_kernel(float* pool, int GC) {
    int i = blockIdx.x * blockDim.x + threadIdx.x;
    if (i < GC) pool[i] = 0.f;
}

// block b covers nodes [b*128,(b+1)*128); thread t owns channel t.
// batch sorted -> few segment flushes per block (~1-2 atomics/channel/block).
__global__ void pool_partial_kernel(const unsigned short* __restrict__ h3,
                                    const int* __restrict__ batch,
                                    float* __restrict__ pool, int N, int G) {
    int lo = blockIdx.x * 128;
    int hi = lo + 128;
    if (hi > N) hi = N;
    if (lo >= N) return;
    int t = threadIdx.x;  // 128
    int cur = batch[lo];
    float acc = 0.f;
    for (int n = lo; n < hi; n++) {
        int g = batch[n];
        if (g != cur) {
            if ((unsigned)cur < (unsigned)G) atomicAdd(&pool[cur * 128 + t], acc);
            acc = 0.f;
            cur = g;
        }
        acc += b2f(h3[(size_t)n * 128 + t]);
    }
    if ((unsigned)cur < (unsigned)G) atomicAdd(&pool[cur * 128 + t], acc);
}

__global__ void head_kernel(const float* __restrict__ pool,
                            const int* __restrict__ batch,
                            const float* __restrict__ Wout,
                            const float* __restrict__ bout,
                            float* __restrict__ out, int N) {
    int g = blockIdx.x;
    int t = threadIdx.x;  // 128
    int lo, hi;
    {
        int a = 0, b = N;
        while (a < b) { int mid = (a + b) >> 1; if (batch[mid] < g) a = mid + 1; else b = mid; }
        lo = a;
        a = lo; b = N;
        while (a < b) { int mid = (a + b) >> 1; if (batch[mid] < g + 1) a = mid + 1; else b = mid; }
        hi = a;
    }
    float c = (float)(hi - lo);
    c = c > 1.f ? c : 1.f;
    float v = (pool[g * 128 + t] / c) * Wout[t];
    for (int o = 32; o; o >>= 1) v += __shfl_xor(v, o);
    __shared__ float partial[2];
    if ((t & 63) == 0) partial[t >> 6] = v;
    __syncthreads();
    if (t == 0) out[g] = partial[0] + partial[1] + bout[0];
}

// ---------------------------- host orchestration ----------------------------
extern "C" void kernel_launch(void* const* d_in, const int* in_sizes, int n_in,
                              void* d_out, int out_size, void* d_ws,
                              size_t ws_size, hipStream_t stream) {
    const float* x = (const float*)d_in[0];
    const int* ei = (const int*)d_in[1];
    const int* batch = (const int*)d_in[2];
    const float* W1 = (const float*)d_in[3];
    const float* a1s = (const float*)d_in[4];
    const float* a1d = (const float*)d_in[5];
    const float* b1 = (const float*)d_in[6];
    const float* W2 = (const float*)d_in[7];
    const float* a2s = (const float*)d_in[8];
    const float* a2d = (const float*)d_in[9];
    const float* b2 = (const float*)d_in[10];
    const float* W3 = (const float*)d_in[11];
    const float* a3s = (const float*)d_in[12];
    const float* a3d = (const float*)d_in[13];
    const float* b3 = (const float*)d_in[14];
    const float* Wout = (const float*)d_in[15];
    const float* bout = (const float*)d_in[16];
    float* out = (float*)d_out;

    const int N = in_sizes[0] / 11;
    const int E = in_sizes[1] / 2;
    const int Etot = E + N;
    const int G = out_size;
    const int NB = (N + 255) / 256;

    char* ws = (char*)d_ws;
    size_t off = 0;
    auto alloc = [&](size_t bytes) -> void* {
        void* p = ws + off;
        off += (bytes + 255) & ~(size_t)255;
        return p;
    };
    unsigned short* buf1 = (unsigned short*)alloc((size_t)N * 1024 * 2);  // h
    unsigned short* buf2 = (unsigned short*)alloc((size_t)N * 1024 * 2);  // out
    float* als = (float*)alloc((size_t)N * 8 * 4);
    float* ald = (float*)alloc((size_t)N * 8 * 4);
    float* mv = (float*)alloc((size_t)N * 8 * 4);
    float* dinv = (float*)alloc((size_t)N * 8 * 4);
    float* escr = (float*)alloc((size_t)Etot * 8 * 4);
    int* rowst = (int*)alloc((size_t)(N + 1) * 4);
    int* cursor = (int*)alloc((size_t)N * 4);
    int* ids = (int*)alloc((size_t)Etot * 4);
    int* deg = (int*)alloc((size_t)N * 4);
    int* bsum = (int*)alloc((size_t)NB * 4);
    int* boff = (int*)alloc((size_t)NB * 4);
    float* pool = (float*)alloc((size_t)G * 128 * 4);
    unsigned short* wt2 = (unsigned short*)alloc((size_t)1024 * 512 * 2);
    unsigned short* wt3 = (unsigned short*)alloc((size_t)512 * 128 * 2);

    int nb = (N + 255) / 256;
    int eb = (E + 255) / 256;

    // ---- CSR by dst (self-loop id = E+n at row head) ----
    init_deg_kernel<<<nb, 256, 0, stream>>>(deg, N);
    hist_kernel<<<eb, 256, 0, stream>>>(ei, E, N, deg);
    scan_block_kernel<<<NB, 256, 0, stream>>>(deg, rowst, bsum, N);
    scan_top_kernel<<<1, 64, 0, stream>>>(bsum, boff, NB);
    scan_add_kernel<<<NB, 256, 0, stream>>>(rowst, boff, N);
    selfloop_kernel<<<nb, 256, 0, stream>>>(rowst, ids, cursor, N, E);
    scatter_kernel<<<eb, 256, 0, stream>>>(ei, E, N, cursor, ids);

    // ---- weight transposes ----
    transpose_w_kernel<<<(1024 * 512 + 255) / 256, 256, 0, stream>>>(W2, wt2,
                                                                     1024, 512);
    transpose_w_kernel<<<(512 * 128 + 255) / 256, 256, 0, stream>>>(W3, wt3,
                                                                    512, 128);

    // ---- Layer 1: x [N,11] -> h1=buf1 [N,1024]; H=8,C=128 -> out1=buf2 ----
    gemm_k11<<<(N * 1024 + 255) / 256, 256, 0, stream>>>(x, W1, buf1, N);
    al_kernel<<<(N * 8 + 3) / 4, 256, 0, stream>>>(buf1, a1s, a1d, als, ald,
                                                   N * 8, 8, 128);
    mden_kernel<8><<<(N * 8 + 255) / 256, 256, 0, stream>>>(als, ald, rowst, ids,
                                                            ei, mv, dinv, E, N);
    alpha_kernel<8><<<(Etot * 8 + 255) / 256, 256, 0, stream>>>(ei, als, ald, mv,
                                                                dinv, escr, E, N);
    agg_kernel4<8, 128><<<N, 256, 0, stream>>>(buf1, escr, rowst, ids, ei, b1,
                                               buf2, E, N);

    // ---- Layer 2: out1 [N,1024] @ W2 -> h2=buf1 [N,512]; H=8,C=64 ----
    gemm_mfma<<<dim3(512 / 128, (N + 127) / 128), 256, 0, stream>>>(
        buf2, wt2, buf1, N, 512, 1024);
    al_kernel<<<(N * 8 + 3) / 4, 256, 0, stream>>>(buf1, a2s, a2d, als, ald,
                                                   N * 8, 8, 64);
    mden_kernel<8><<<(N * 8 + 255) / 256, 256, 0, stream>>>(als, ald, rowst, ids,
                                                            ei, mv, dinv, E, N);
    alpha_kernel<8><<<(Etot * 8 + 255) / 256, 256, 0, stream>>>(ei, als, ald, mv,
                                                                dinv, escr, E, N);
    agg_kernel4<8, 64><<<N, 128, 0, stream>>>(buf1, escr, rowst, ids, ei, b2,
                                              buf2, E, N);

    // ---- Layer 3: out2 [N,512] @ W3 -> h3=buf1 [N,128]; H=4,C=32 ----
    gemm_mfma<<<dim3(128 / 128, (N + 127) / 128), 256, 0, stream>>>(
        buf2, wt3, buf1, N, 128, 512);
    al_kernel<<<(N * 4 + 3) / 4, 256, 0, stream>>>(buf1, a3s, a3d, als, ald,
                                                   N * 4, 4, 32);
    mden_kernel<4><<<(N * 4 + 255) / 256, 256, 0, stream>>>(als, ald, rowst, ids,
                                                            ei, mv, dinv, E, N);
    alpha_kernel<4><<<(Etot * 4 + 255) / 256, 256, 0, stream>>>(ei, als, ald, mv,
                                                                dinv, escr, E, N);
    agg_kernel2<4, 32, 64><<<N, 64, 0, stream>>>(buf1, escr, rowst, ids, ei, b3,
                                                 buf2, E, N);

    // ---- parallel mean-pool + head ----
    pool_init_kernel<<<(G * 128 + 255) / 256, 256, 0, stream>>>(pool, G * 128);
    pool_partial_kernel<<<(N + 127) / 128, 128, 0, stream>>>(buf2, batch, pool,
                                                             N, G);
    head_kernel<<<G, 128, 0, stream>>>(pool, batch, Wout, bout, out, N);
}

// Round 9
// 812.170 us; speedup vs baseline: 3.1461x; 1.1430x over previous
//
#include <hip/hip_runtime.h>

#define EPS 1e-16f

typedef __attribute__((ext_vector_type(8))) short short8;
typedef __attribute__((ext_vector_type(4))) float f32x4;

// ---------- bf16 <-> fp32 (internal storage only) ----------
__device__ __forceinline__ float b2f(unsigned short u) {
    return __uint_as_float(((unsigned)u) << 16);
}
__device__ __forceinline__ unsigned short f2b(float f) {
    unsigned u = __float_as_uint(f);
    u += 0x7fffu + ((u >> 16) & 1u);  // round-to-nearest-even
    return (unsigned short)(u >> 16);
}

// ---------------------------- CSR build ----------------------------
__global__ void init_deg_kernel(int* deg, int N) {
    int i = blockIdx.x * blockDim.x + threadIdx.x;
    if (i < N) deg[i] = 1;  // self-loop
}

__global__ void hist_kernel(const int* __restrict__ ei, int E, int N, int* deg) {
    int e = blockIdx.x * blockDim.x + threadIdx.x;
    if (e < E) {
        int d = ei[E + e];
        if ((unsigned)d < (unsigned)N) atomicAdd(&deg[d], 1);
    }
}

// phase 1: per-block inclusive scan of 256 elems -> rowst[i+1]; total -> bsum[b]
__global__ void scan_block_kernel(const int* __restrict__ deg,
                                  int* __restrict__ rowst,
                                  int* __restrict__ bsum, int N) {
    __shared__ int s[256];
    int t = threadIdx.x, b = blockIdx.x;
    int i = b * 256 + t;
    s[t] = (i < N) ? deg[i] : 0;
    __syncthreads();
    for (int o = 1; o < 256; o <<= 1) {
        int a = (t >= o) ? s[t - o] : 0;
        __syncthreads();
        s[t] += a;
        __syncthreads();
    }
    if (i < N) rowst[i + 1] = s[t];
    if (t == 255) bsum[b] = s[255];
}

// phase 2: one wave exclusive-scans bsum[NB] -> boff
__global__ void scan_top_kernel(const int* __restrict__ bsum,
                                int* __restrict__ boff, int NB) {
    __shared__ int psum[65];
    int t = threadIdx.x;  // 64
    int chunk = (NB + 63) / 64;
    int lo = t * chunk, hi = lo + chunk;
    if (lo > NB) lo = NB;
    if (hi > NB) hi = NB;
    int s = 0;
    for (int i = lo; i < hi; i++) s += bsum[i];
    psum[t + 1] = s;
    __syncthreads();
    if (t == 0) {
        psum[0] = 0;
        for (int i = 1; i <= 64; i++) psum[i] += psum[i - 1];
    }
    __syncthreads();
    int run = psum[t];
    for (int i = lo; i < hi; i++) {
        boff[i] = run;  // exclusive
        run += bsum[i];
    }
}

// phase 3: add block offsets; set rowst[0]=0
__global__ void scan_add_kernel(int* __restrict__ rowst,
                                const int* __restrict__ boff, int N) {
    int i = blockIdx.x * 256 + threadIdx.x;
    if (i == 0) rowst[0] = 0;
    if (i < N) rowst[i + 1] += boff[blockIdx.x];
}

__global__ void selfloop_kernel(const int* __restrict__ rowst, int* ids,
                                int* cursor, int N, int E) {
    int n = blockIdx.x * blockDim.x + threadIdx.x;
    if (n < N) {
        ids[rowst[n]] = E + n;  // self-loop edge id
        cursor[n] = rowst[n] + 1;
    }
}

__global__ void scatter_kernel(const int* __restrict__ ei, int E, int N,
                               int* cursor, int* ids) {
    int e = blockIdx.x * blockDim.x + threadIdx.x;
    if (e < E) {
        int d = ei[E + e];
        if ((unsigned)d < (unsigned)N) {
            int p = atomicAdd(&cursor[d], 1);
            ids[p] = e;
        }
    }
}

// ---------------------------- GEMM prep ----------------------------
// x [N,11] fp32 -> A_pad [N,32] bf16 (K zero-padded 11->32)
__global__ void pad_a1_kernel(const float* __restrict__ x,
                              unsigned short* __restrict__ A, int N) {
    int i = blockIdx.x * blockDim.x + threadIdx.x;
    if (i >= N * 32) return;
    int n = i >> 5, k = i & 31;
    A[i] = (k < 11) ? f2b(x[n * 11 + k]) : 0;
}

// W1 [11,1024] fp32 -> Wt1 [1024,32] bf16 (transposed, K zero-padded)
__global__ void pad_w1_kernel(const float* __restrict__ W,
                              unsigned short* __restrict__ Wt) {
    int i = blockIdx.x * blockDim.x + threadIdx.x;
    if (i >= 1024 * 32) return;
    int n = i >> 5, k = i & 31;
    Wt[i] = (k < 11) ? f2b(W[k * 1024 + n]) : 0;
}

// W [K,N] fp32 -> Wt [N,K] bf16 (bf16-valued fp32 => lossless)
__global__ void transpose_w_kernel(const float* __restrict__ W,
                                   unsigned short* __restrict__ Wt, int K, int N) {
    int i = blockIdx.x * blockDim.x + threadIdx.x;
    if (i >= K * N) return;
    int k = i / N, n = i % N;
    Wt[(size_t)n * K + k] = f2b(W[i]);
}

// MFMA GEMM: C[M,N] = A[M,K] * Bt[N,K]^T. bf16 in/out, fp32 accum.
// BM=BN=128, BK=32; 4 waves each own a 64x64 quadrant. N%128==0, K%32==0.
__global__ __launch_bounds__(256) void gemm_mfma(
    const unsigned short* __restrict__ A, const unsigned short* __restrict__ Bt,
    unsigned short* __restrict__ C, int M, int N, int K) {
    __shared__ unsigned short As[128][40];  // [m][k], +8 pad
    __shared__ unsigned short Bs[128][40];  // [n][k], +8 pad
    int t = threadIdx.x;
    int w = t >> 6, lane = t & 63;
    int quad = lane >> 4, l16 = lane & 15;
    int bm = blockIdx.y * 128, bn = blockIdx.x * 128;
    int wr = (w >> 1) * 64, wc = (w & 1) * 64;
    f32x4 acc[4][4] = {};
    for (int k0 = 0; k0 < K; k0 += 32) {
#pragma unroll
        for (int rep = 0; rep < 2; rep++) {
            int linear = rep * 2048 + t * 8;
            int row = linear >> 5, col = linear & 31;
            int grow = bm + row;
            uint4 v = make_uint4(0, 0, 0, 0);
            if (grow < M) v = *(const uint4*)(A + (size_t)grow * K + k0 + col);
            *(uint4*)&As[row][col] = v;
            uint4 bv = *(const uint4*)(Bt + (size_t)(bn + row) * K + k0 + col);
            *(uint4*)&Bs[row][col] = bv;
        }
        __syncthreads();
        short8 a[4], b[4];
#pragma unroll
        for (int mi = 0; mi < 4; mi++)
            a[mi] = *(const short8*)&As[wr + mi * 16 + l16][quad * 8];
#pragma unroll
        for (int ni = 0; ni < 4; ni++)
            b[ni] = *(const short8*)&Bs[wc + ni * 16 + l16][quad * 8];
#pragma unroll
        for (int mi = 0; mi < 4; mi++)
#pragma unroll
            for (int ni = 0; ni < 4; ni++)
                acc[mi][ni] = __builtin_amdgcn_mfma_f32_16x16x32_bf16(
                    a[mi], b[ni], acc[mi][ni], 0, 0, 0);
        __syncthreads();
    }
#pragma unroll
    for (int mi = 0; mi < 4; mi++) {
#pragma unroll
        for (int r = 0; r < 4; r++) {
            int row = bm + wr + mi * 16 + quad * 4 + r;
            if (row < M) {
#pragma unroll
                for (int ni = 0; ni < 4; ni++) {
                    int col = bn + wc + ni * 16 + l16;
                    C[(size_t)row * N + col] = f2b(acc[mi][ni][r]);
                }
            }
        }
    }
}

// ---------------------------- attention logits ----------------------------
__global__ void al_kernel(const unsigned short* __restrict__ h,
                          const float* __restrict__ a_s,
                          const float* __restrict__ a_d, float* __restrict__ als,
                          float* __restrict__ ald, int NH, int H, int C) {
    int wave = (int)((blockIdx.x * blockDim.x + threadIdx.x) >> 6);
    int lane = threadIdx.x & 63;
    if (wave >= NH) return;
    int n = wave / H, hh = wave % H;
    const unsigned short* hp = h + (size_t)n * H * C + (size_t)hh * C;
    const float* as = a_s + hh * C;
    const float* ad = a_d + hh * C;
    float s = 0.f, d = 0.f;
    for (int c = lane; c < C; c += 64) {
        float v = b2f(hp[c]);
        s += v * as[c];
        d += v * ad[c];
    }
    for (int o = 32; o; o >>= 1) {
        s += __shfl_xor(s, o);
        d += __shfl_xor(d, o);
    }
    if (lane == 0) { als[wave] = s; ald[wave] = d; }
}

// ---------------- softmax: per-(n,h) max & inv-denominator ----------------
template <int H>
__global__ void mden_kernel(const float* __restrict__ als,
                            const float* __restrict__ ald,
                            const int* __restrict__ rowst,
                            const int* __restrict__ ids,
                            const int* __restrict__ ei, float* __restrict__ mv,
                            float* __restrict__ dinv, int E, int N) {
    int i = blockIdx.x * blockDim.x + threadIdx.x;
    if (i >= N * H) return;
    int n = i / H, h = i % H;
    float aldn = ald[i];
    int start = rowst[n], end = rowst[n + 1];
    float v0 = als[n * H + h] + aldn;  // self-loop logit (always present)
    float m = v0 > 0.f ? v0 : 0.2f * v0;
    for (int idx = start; idx < end; ++idx) {
        int e = ids[idx];
        int s = (e < E) ? ei[e] : n;
        if ((unsigned)s >= (unsigned)N) s = n;
        float v = als[s * H + h] + aldn;
        v = v > 0.f ? v : 0.2f * v;
        m = fmaxf(m, v);
    }
    float den = 0.f;
    for (int idx = start; idx < end; ++idx) {
        int e = ids[idx];
        int s = (e < E) ? ei[e] : n;
        if ((unsigned)s >= (unsigned)N) s = n;
        float v = als[s * H + h] + aldn;
        v = v > 0.f ? v : 0.2f * v;
        den += expf(v - m);
    }
    mv[i] = m;
    dinv[i] = 1.0f / (den + EPS);
}

// ---------------------- per-(edge,head) alpha ----------------------
template <int H>
__global__ void alpha_kernel(const int* __restrict__ ei,
                             const float* __restrict__ als,
                             const float* __restrict__ ald,
                             const float* __restrict__ mv,
                             const float* __restrict__ dinv,
                             float* __restrict__ escr, int E, int N) {
    int i = blockIdx.x * blockDim.x + threadIdx.x;
    if (i >= (E + N) * H) return;
    int e = i / H, h = i % H;
    int s, d;
    if (e < E) {
        s = ei[e];
        d = ei[E + e];
        if ((unsigned)d >= (unsigned)N) { escr[i] = 0.f; return; }
        if ((unsigned)s >= (unsigned)N) s = d;
    } else {
        s = d = e - E;
    }
    float v = als[s * H + h] + ald[d * H + h];
    v = v > 0.f ? v : 0.2f * v;
    escr[i] = expf(v - mv[d * H + h]) * dinv[d * H + h];
}

// ---------------------- single-pass aggregation, ushort4 ----------------------
template <int H, int C>
__global__ void agg_kernel4(const unsigned short* __restrict__ hin,
                            const float* __restrict__ escr,
                            const int* __restrict__ rowst,
                            const int* __restrict__ ids,
                            const int* __restrict__ ei,
                            const float* __restrict__ bias,
                            unsigned short* __restrict__ out, int E, int N) {
    constexpr int HC = H * C;
    int n = blockIdx.x;
    int t = threadIdx.x;  // HC/4 threads
    int c = t * 4;
    int hh = c / C;
    int start = rowst[n], end = rowst[n + 1];
    float a0 = 0.f, a1 = 0.f, a2 = 0.f, a3 = 0.f;
    for (int idx = start; idx < end; ++idx) {
        int e = ids[idx];
        int s = (e < E) ? ei[e] : n;
        if ((unsigned)s >= (unsigned)N) s = n;
        float a = escr[(size_t)e * H + hh];
        ushort4 u = *(const ushort4*)(hin + (size_t)s * HC + c);
        a0 += a * b2f(u.x);
        a1 += a * b2f(u.y);
        a2 += a * b2f(u.z);
        a3 += a * b2f(u.w);
    }
    float v0 = a0 + bias[c], v1 = a1 + bias[c + 1];
    float v2 = a2 + bias[c + 2], v3 = a3 + bias[c + 3];
    ushort4 o;
    o.x = f2b(v0 > 0.f ? v0 : 0.01f * v0);
    o.y = f2b(v1 > 0.f ? v1 : 0.01f * v1);
    o.z = f2b(v2 > 0.f ? v2 : 0.01f * v2);
    o.w = f2b(v3 > 0.f ? v3 : 0.01f * v3);
    *(ushort4*)&out[(size_t)n * HC + c] = o;
}

// ushort2 variant for small HC (layer 3: HC=128, TPB=64)
template <int H, int C, int TPB>
__global__ void agg_kernel2(const unsigned short* __restrict__ hin,
                            const float* __restrict__ escr,
                            const int* __restrict__ rowst,
                            const int* __restrict__ ids,
                            const int* __restrict__ ei,
                            const float* __restrict__ bias,
                            unsigned short* __restrict__ out, int E, int N) {
    constexpr int HC = H * C;
    int n = blockIdx.x;
    int t = threadIdx.x;
    int c = t * 2;
    int hh = c / C;
    int start = rowst[n], end = rowst[n + 1];
    float a0 = 0.f, a1 = 0.f;
    for (int idx = start; idx < end; ++idx) {
        int e = ids[idx];
        int s = (e < E) ? ei[e] : n;
        if ((unsigned)s >= (unsigned)N) s = n;
        float a = escr[(size_t)e * H + hh];
        ushort2 u = *(const ushort2*)(hin + (size_t)s * HC + c);
        a0 += a * b2f(u.x);
        a1 += a * b2f(u.y);
    }
    float v0 = a0 + bias[c], v1 = a1 + bias[c + 1];
    ushort2 o;
    o.x = f2b(v0 > 0.f ? v0 : 0.01f * v0);
    o.y = f2b(v1 > 0.f ? v1 : 0.01f * v1);
    *(ushort2*)&out[(size_t)n * HC + c] = o;
}

// ---------------------- parallel mean-pool + head ----------------------
__global__ void pool_init_kernel(float* pool, int GC) {
    int i = blockIdx.x * blockDim.x + threadIdx.x;
    if (i < GC) pool[i] = 0.f;
}

__global__ void pool_partial_kernel(const unsigned short* __restrict__ h3,
                                    const int* __restrict__ batch,
                                    float* __restrict__ pool, int N, int G) {
    int lo = blockIdx.x * 128;
    int hi = lo + 128;
    if (hi > N) hi = N;
    if (lo >= N) return;
    int t = threadIdx.x;  // 128
    int cur = batch[lo];
    float acc = 0.f;
    for (int n = lo; n < hi; n++) {
        int g = batch[n];
        if (g != cur) {
            if ((unsigned)cur < (unsigned)G) atomicAdd(&pool[cur * 128 + t], acc);
            acc = 0.f;
            cur = g;
        }
        acc += b2f(h3[(size_t)n * 128 + t]);
    }
    if ((unsigned)cur < (unsigned)G) atomicAdd(&pool[cur * 128 + t], acc);
}

__global__ void head_kernel(const float* __restrict__ pool,
                            const int* __restrict__ batch,
                            const float* __restrict__ Wout,
                            const float* __restrict__ bout,
                            float* __restrict__ out, int N) {
    int g = blockIdx.x;
    int t = threadIdx.x;  // 128
    int lo, hi;
    {
        int a = 0, b = N;
        while (a < b) { int mid = (a + b) >> 1; if (batch[mid] < g) a = mid + 1; else b = mid; }
        lo = a;
        a = lo; b = N;
        while (a < b) { int mid = (a + b) >> 1; if (batch[mid] < g + 1) a = mid + 1; else b = mid; }
        hi = a;
    }
    float c = (float)(hi - lo);
    c = c > 1.f ? c : 1.f;
    float v = (pool[g * 128 + t] / c) * Wout[t];
    for (int o = 32; o; o >>= 1) v += __shfl_xor(v, o);
    __shared__ float partial[2];
    if ((t & 63) == 0) partial[t >> 6] = v;
    __syncthreads();
    if (t == 0) out[g] = partial[0] + partial[1] + bout[0];
}

// ---------------------------- host orchestration ----------------------------
extern "C" void kernel_launch(void* const* d_in, const int* in_sizes, int n_in,
                              void* d_out, int out_size, void* d_ws,
                              size_t ws_size, hipStream_t stream) {
    const float* x = (const float*)d_in[0];
    const int* ei = (const int*)d_in[1];
    const int* batch = (const int*)d_in[2];
    const float* W1 = (const float*)d_in[3];
    const float* a1s = (const float*)d_in[4];
    const float* a1d = (const float*)d_in[5];
    const float* b1 = (const float*)d_in[6];
    const float* W2 = (const float*)d_in[7];
    const float* a2s = (const float*)d_in[8];
    const float* a2d = (const float*)d_in[9];
    const float* b2 = (const float*)d_in[10];
    const float* W3 = (const float*)d_in[11];
    const float* a3s = (const float*)d_in[12];
    const float* a3d = (const float*)d_in[13];
    const float* b3 = (const float*)d_in[14];
    const float* Wout = (const float*)d_in[15];
    const float* bout = (const float*)d_in[16];
    float* out = (float*)d_out;

    const int N = in_sizes[0] / 11;
    const int E = in_sizes[1] / 2;
    const int Etot = E + N;
    const int G = out_size;
    const int NB = (N + 255) / 256;

    char* ws = (char*)d_ws;
    size_t off = 0;
    auto alloc = [&](size_t bytes) -> void* {
        void* p = ws + off;
        off += (bytes + 255) & ~(size_t)255;
        return p;
    };
    unsigned short* buf1 = (unsigned short*)alloc((size_t)N * 1024 * 2);  // h
    unsigned short* buf2 = (unsigned short*)alloc((size_t)N * 1024 * 2);  // out
    float* als = (float*)alloc((size_t)N * 8 * 4);
    float* ald = (float*)alloc((size_t)N * 8 * 4);
    float* mv = (float*)alloc((size_t)N * 8 * 4);
    float* dinv = (float*)alloc((size_t)N * 8 * 4);
    float* escr = (float*)alloc((size_t)Etot * 8 * 4);
    int* rowst = (int*)alloc((size_t)(N + 1) * 4);
    int* cursor = (int*)alloc((size_t)N * 4);
    int* ids = (int*)alloc((size_t)Etot * 4);
    int* deg = (int*)alloc((size_t)N * 4);
    int* bsum = (int*)alloc((size_t)NB * 4);
    int* boff = (int*)alloc((size_t)NB * 4);
    float* pool = (float*)alloc((size_t)G * 128 * 4);
    unsigned short* apad = (unsigned short*)alloc((size_t)N * 32 * 2);
    unsigned short* wt1 = (unsigned short*)alloc((size_t)1024 * 32 * 2);
    unsigned short* wt2 = (unsigned short*)alloc((size_t)1024 * 512 * 2);
    unsigned short* wt3 = (unsigned short*)alloc((size_t)512 * 128 * 2);

    int nb = (N + 255) / 256;
    int eb = (E + 255) / 256;

    // ---- CSR by dst (self-loop id = E+n at row head) ----
    init_deg_kernel<<<nb, 256, 0, stream>>>(deg, N);
    hist_kernel<<<eb, 256, 0, stream>>>(ei, E, N, deg);
    scan_block_kernel<<<NB, 256, 0, stream>>>(deg, rowst, bsum, N);
    scan_top_kernel<<<1, 64, 0, stream>>>(bsum, boff, NB);
    scan_add_kernel<<<NB, 256, 0, stream>>>(rowst, boff, N);
    selfloop_kernel<<<nb, 256, 0, stream>>>(rowst, ids, cursor, N, E);
    scatter_kernel<<<eb, 256, 0, stream>>>(ei, E, N, cursor, ids);

    // ---- weight prep ----
    pad_a1_kernel<<<(N * 32 + 255) / 256, 256, 0, stream>>>(x, apad, N);
    pad_w1_kernel<<<(1024 * 32 + 255) / 256, 256, 0, stream>>>(W1, wt1);
    transpose_w_kernel<<<(1024 * 512 + 255) / 256, 256, 0, stream>>>(W2, wt2,
                                                                     1024, 512);
    transpose_w_kernel<<<(512 * 128 + 255) / 256, 256, 0, stream>>>(W3, wt3,
                                                                    512, 128);

    // ---- Layer 1: A_pad [N,32] @ Wt1 -> h1=buf1 [N,1024]; H=8,C=128 ----
    gemm_mfma<<<dim3(1024 / 128, (N + 127) / 128), 256, 0, stream>>>(
        apad, wt1, buf1, N, 1024, 32);
    al_kernel<<<(N * 8 + 3) / 4, 256, 0, stream>>>(buf1, a1s, a1d, als, ald,
                                                   N * 8, 8, 128);
    mden_kernel<8><<<(N * 8 + 255) / 256, 256, 0, stream>>>(als, ald, rowst, ids,
                                                            ei, mv, dinv, E, N);
    alpha_kernel<8><<<(Etot * 8 + 255) / 256, 256, 0, stream>>>(ei, als, ald, mv,
                                                                dinv, escr, E, N);
    agg_kernel4<8, 128><<<N, 256, 0, stream>>>(buf1, escr, rowst, ids, ei, b1,
                                               buf2, E, N);

    // ---- Layer 2: out1 [N,1024] @ W2 -> h2=buf1 [N,512]; H=8,C=64 ----
    gemm_mfma<<<dim3(512 / 128, (N + 127) / 128), 256, 0, stream>>>(
        buf2, wt2, buf1, N, 512, 1024);
    al_kernel<<<(N * 8 + 3) / 4, 256, 0, stream>>>(buf1, a2s, a2d, als, ald,
                                                   N * 8, 8, 64);
    mden_kernel<8><<<(N * 8 + 255) / 256, 256, 0, stream>>>(als, ald, rowst, ids,
                                                            ei, mv, dinv, E, N);
    alpha_kernel<8><<<(Etot * 8 + 255) / 256, 256, 0, stream>>>(ei, als, ald, mv,
                                                                dinv, escr, E, N);
    agg_kernel4<8, 64><<<N, 128, 0, stream>>>(buf1, escr, rowst, ids, ei, b2,
                                              buf2, E, N);

    // ---- Layer 3: out2 [N,512] @ W3 -> h3=buf1 [N,128]; H=4,C=32 ----
    gemm_mfma<<<dim3(128 / 128, (N + 127) / 128), 256, 0, stream>>>(
        buf2, wt3, buf1, N, 128, 512);
    al_kernel<<<(N * 4 + 3) / 4, 256, 0, stream>>>(buf1, a3s, a3d, als, ald,
                                                   N * 4, 4, 32);
    mden_kernel<4><<<(N * 4 + 255) / 256, 256, 0, stream>>>(als, ald, rowst, ids,
                                                            ei, mv, dinv, E, N);
    alpha_kernel<4><<<(Etot * 4 + 255) / 256, 256, 0, stream>>>(ei, als, ald, mv,
                                                                dinv, escr, E, N);
    agg_kernel2<4, 32, 64><<<N, 64, 0, stream>>>(buf1, escr, rowst, ids, ei, b3,
                                                 buf2, E, N);

    // ---- parallel mean-pool + head ----
    pool_init_kernel<<<(G * 128 + 255) / 256, 256, 0, stream>>>(pool, G * 128);
    pool_partial_kernel<<<(N + 127) / 128, 128, 0, stream>>>(buf2, batch, pool,
                                                             N, G);
    head_kernel<<<G, 128, 0, stream>>>(pool, batch, Wout, bout, out, N);
}

// Round 10
// 696.089 us; speedup vs baseline: 3.6707x; 1.1668x over previous
//
#include <hip/hip_runtime.h>

#define EPS 1e-16f

typedef __attribute__((ext_vector_type(8))) short short8;
typedef __attribute__((ext_vector_type(4))) float f32x4;

// ---------- bf16 <-> fp32 (internal storage only) ----------
__device__ __forceinline__ float b2f(unsigned short u) {
    return __uint_as_float(((unsigned)u) << 16);
}
__device__ __forceinline__ unsigned short f2b(float f) {
    unsigned u = __float_as_uint(f);
    u += 0x7fffu + ((u >> 16) & 1u);  // round-to-nearest-even
    return (unsigned short)(u >> 16);
}

// ---------------------------- CSR build ----------------------------
__global__ void init_deg_kernel(int* deg, int N) {
    int i = blockIdx.x * blockDim.x + threadIdx.x;
    if (i < N) deg[i] = 1;  // self-loop
}

__global__ void hist_kernel(const int* __restrict__ ei, int E, int N, int* deg) {
    int e = blockIdx.x * blockDim.x + threadIdx.x;
    if (e < E) {
        int d = ei[E + e];
        if ((unsigned)d < (unsigned)N) atomicAdd(&deg[d], 1);
    }
}

__global__ void scan_block_kernel(const int* __restrict__ deg,
                                  int* __restrict__ rowst,
                                  int* __restrict__ bsum, int N) {
    __shared__ int s[256];
    int t = threadIdx.x, b = blockIdx.x;
    int i = b * 256 + t;
    s[t] = (i < N) ? deg[i] : 0;
    __syncthreads();
    for (int o = 1; o < 256; o <<= 1) {
        int a = (t >= o) ? s[t - o] : 0;
        __syncthreads();
        s[t] += a;
        __syncthreads();
    }
    if (i < N) rowst[i + 1] = s[t];
    if (t == 255) bsum[b] = s[255];
}

__global__ void scan_top_kernel(const int* __restrict__ bsum,
                                int* __restrict__ boff, int NB) {
    __shared__ int psum[65];
    int t = threadIdx.x;  // 64
    int chunk = (NB + 63) / 64;
    int lo = t * chunk, hi = lo + chunk;
    if (lo > NB) lo = NB;
    if (hi > NB) hi = NB;
    int s = 0;
    for (int i = lo; i < hi; i++) s += bsum[i];
    psum[t + 1] = s;
    __syncthreads();
    if (t == 0) {
        psum[0] = 0;
        for (int i = 1; i <= 64; i++) psum[i] += psum[i - 1];
    }
    __syncthreads();
    int run = psum[t];
    for (int i = lo; i < hi; i++) {
        boff[i] = run;  // exclusive
        run += bsum[i];
    }
}

__global__ void scan_add_kernel(int* __restrict__ rowst,
                                const int* __restrict__ boff, int N) {
    int i = blockIdx.x * 256 + threadIdx.x;
    if (i == 0) rowst[0] = 0;
    if (i < N) rowst[i + 1] += boff[blockIdx.x];
}

__global__ void selfloop_kernel(const int* __restrict__ rowst, int* ids,
                                int* cursor, int N, int E) {
    int n = blockIdx.x * blockDim.x + threadIdx.x;
    if (n < N) {
        ids[rowst[n]] = E + n;  // self-loop edge id
        cursor[n] = rowst[n] + 1;
    }
}

__global__ void scatter_kernel(const int* __restrict__ ei, int E, int N,
                               int* cursor, int* ids) {
    int e = blockIdx.x * blockDim.x + threadIdx.x;
    if (e < E) {
        int d = ei[E + e];
        if ((unsigned)d < (unsigned)N) {
            int p = atomicAdd(&cursor[d], 1);
            ids[p] = e;
        }
    }
}

// ---------------------------- layer-1 specials ----------------------------
// w_as[h,k] = sum_c W1[k, h*128+c] * a1s[h,c]; same for a1d. Stored [8][16].
__global__ void wa1_kernel(const float* __restrict__ W1,
                           const float* __restrict__ a1s,
                           const float* __restrict__ a1d,
                           float* __restrict__ w_as, float* __restrict__ w_ad) {
    int t = threadIdx.x;  // 128; active t<88
    if (t >= 88) return;
    int h = t / 11, k = t % 11;
    float s = 0.f, d = 0.f;
    for (int c = 0; c < 128; c++) {
        float w = W1[k * 1024 + h * 128 + c];
        s += w * a1s[h * 128 + c];
        d += w * a1d[h * 128 + c];
    }
    w_as[h * 16 + k] = s;
    w_ad[h * 16 + k] = d;
}

// als[n,h] = x[n,:11] . w_as[h,:11]
__global__ void al1_kernel(const float* __restrict__ x,
                           const float* __restrict__ w_as,
                           const float* __restrict__ w_ad,
                           float* __restrict__ als, float* __restrict__ ald,
                           int N) {
    int i = blockIdx.x * blockDim.x + threadIdx.x;
    if (i >= N * 8) return;
    int n = i >> 3, h = i & 7;
    float s = 0.f, d = 0.f;
#pragma unroll
    for (int k = 0; k < 11; k++) {
        float xv = x[n * 11 + k];
        s += xv * w_as[h * 16 + k];
        d += xv * w_ad[h * 16 + k];
    }
    als[i] = s;
    ald[i] = d;
}

// aggx[n, h*16+k] = bf16( sum_e alpha[e,h] * x[src_e, k] ), k<11 else 0.
// One block (128 thr) per node.
__global__ void aggx_kernel(const float* __restrict__ x,
                            const float* __restrict__ escr,
                            const int* __restrict__ rowst,
                            const int* __restrict__ ids,
                            const int* __restrict__ ei,
                            unsigned short* __restrict__ A2, int E, int N) {
    int n = blockIdx.x;
    int t = threadIdx.x;  // 128
    int h = t >> 4, k = t & 15;
    int start = rowst[n], end = rowst[n + 1];
    float acc = 0.f;
    for (int idx = start; idx < end; ++idx) {
        int e = ids[idx];
        int s = (e < E) ? ei[e] : n;
        if ((unsigned)s >= (unsigned)N) s = n;
        float a = escr[(size_t)e * 8 + h];
        float xv = (k < 11) ? x[s * 11 + k] : 0.f;
        acc += a * xv;
    }
    A2[(size_t)n * 128 + t] = f2b(acc);
}

// W1' block-diagonal, Bt layout [1024][128]: Bt[n][h*16+k] = (h==n>>7 && k<11) ? W1[k,n] : 0
__global__ void w1bd_kernel(const float* __restrict__ W1,
                            unsigned short* __restrict__ Bt) {
    int i = blockIdx.x * blockDim.x + threadIdx.x;
    if (i >= 1024 * 128) return;
    int n = i >> 7, kk = i & 127;
    int h = kk >> 4, k = kk & 15;
    float v = (h == (n >> 7) && k < 11) ? W1[k * 1024 + n] : 0.f;
    Bt[i] = f2b(v);
}

// ---------------------------- GEMM prep ----------------------------
// W [K,N] fp32 -> Wt [N,K] bf16 (bf16-valued fp32 => lossless)
__global__ void transpose_w_kernel(const float* __restrict__ W,
                                   unsigned short* __restrict__ Wt, int K, int N) {
    int i = blockIdx.x * blockDim.x + threadIdx.x;
    if (i >= K * N) return;
    int k = i / N, n = i % N;
    Wt[(size_t)n * K + k] = f2b(W[i]);
}

// MFMA GEMM: C[M,N] = A[M,K] * Bt[N,K]^T. bf16 in/out, fp32 accum.
// BM=BN=128, BK=32; 4 waves each own a 64x64 quadrant. N%128==0, K%32==0.
// EPI: fused C = leaky01(acc + bias[col]).
template <bool EPI>
__global__ __launch_bounds__(256) void gemm_mfma(
    const unsigned short* __restrict__ A, const unsigned short* __restrict__ Bt,
    unsigned short* __restrict__ C, const float* __restrict__ bias, int M,
    int N, int K) {
    __shared__ unsigned short As[128][40];  // [m][k], +8 pad
    __shared__ unsigned short Bs[128][40];  // [n][k], +8 pad
    int t = threadIdx.x;
    int w = t >> 6, lane = t & 63;
    int quad = lane >> 4, l16 = lane & 15;
    int bm = blockIdx.y * 128, bn = blockIdx.x * 128;
    int wr = (w >> 1) * 64, wc = (w & 1) * 64;
    f32x4 acc[4][4] = {};
    for (int k0 = 0; k0 < K; k0 += 32) {
#pragma unroll
        for (int rep = 0; rep < 2; rep++) {
            int linear = rep * 2048 + t * 8;
            int row = linear >> 5, col = linear & 31;
            int grow = bm + row;
            uint4 v = make_uint4(0, 0, 0, 0);
            if (grow < M) v = *(const uint4*)(A + (size_t)grow * K + k0 + col);
            *(uint4*)&As[row][col] = v;
            uint4 bv = *(const uint4*)(Bt + (size_t)(bn + row) * K + k0 + col);
            *(uint4*)&Bs[row][col] = bv;
        }
        __syncthreads();
        short8 a[4], b[4];
#pragma unroll
        for (int mi = 0; mi < 4; mi++)
            a[mi] = *(const short8*)&As[wr + mi * 16 + l16][quad * 8];
#pragma unroll
        for (int ni = 0; ni < 4; ni++)
            b[ni] = *(const short8*)&Bs[wc + ni * 16 + l16][quad * 8];
#pragma unroll
        for (int mi = 0; mi < 4; mi++)
#pragma unroll
            for (int ni = 0; ni < 4; ni++)
                acc[mi][ni] = __builtin_amdgcn_mfma_f32_16x16x32_bf16(
                    a[mi], b[ni], acc[mi][ni], 0, 0, 0);
        __syncthreads();
    }
#pragma unroll
    for (int mi = 0; mi < 4; mi++) {
#pragma unroll
        for (int r = 0; r < 4; r++) {
            int row = bm + wr + mi * 16 + quad * 4 + r;
            if (row < M) {
#pragma unroll
                for (int ni = 0; ni < 4; ni++) {
                    int col = bn + wc + ni * 16 + l16;
                    float v = acc[mi][ni][r];
                    if (EPI) {
                        v += bias[col];
                        v = v > 0.f ? v : 0.01f * v;
                    }
                    C[(size_t)row * N + col] = f2b(v);
                }
            }
        }
    }
}

// ---------------------------- attention logits ----------------------------
__global__ void al_kernel(const unsigned short* __restrict__ h,
                          const float* __restrict__ a_s,
                          const float* __restrict__ a_d, float* __restrict__ als,
                          float* __restrict__ ald, int NH, int H, int C) {
    int wave = (int)((blockIdx.x * blockDim.x + threadIdx.x) >> 6);
    int lane = threadIdx.x & 63;
    if (wave >= NH) return;
    int n = wave / H, hh = wave % H;
    const unsigned short* hp = h + (size_t)n * H * C + (size_t)hh * C;
    const float* as = a_s + hh * C;
    const float* ad = a_d + hh * C;
    float s = 0.f, d = 0.f;
    for (int c = lane; c < C; c += 64) {
        float v = b2f(hp[c]);
        s += v * as[c];
        d += v * ad[c];
    }
    for (int o = 32; o; o >>= 1) {
        s += __shfl_xor(s, o);
        d += __shfl_xor(d, o);
    }
    if (lane == 0) { als[wave] = s; ald[wave] = d; }
}

// ---------------- softmax: per-(n,h) max & inv-denominator ----------------
template <int H>
__global__ void mden_kernel(const float* __restrict__ als,
                            const float* __restrict__ ald,
                            const int* __restrict__ rowst,
                            const int* __restrict__ ids,
                            const int* __restrict__ ei, float* __restrict__ mv,
                            float* __restrict__ dinv, int E, int N) {
    int i = blockIdx.x * blockDim.x + threadIdx.x;
    if (i >= N * H) return;
    int n = i / H, h = i % H;
    float aldn = ald[i];
    int start = rowst[n], end = rowst[n + 1];
    float v0 = als[n * H + h] + aldn;  // self-loop logit (always present)
    float m = v0 > 0.f ? v0 : 0.2f * v0;
    for (int idx = start; idx < end; ++idx) {
        int e = ids[idx];
        int s = (e < E) ? ei[e] : n;
        if ((unsigned)s >= (unsigned)N) s = n;
        float v = als[s * H + h] + aldn;
        v = v > 0.f ? v : 0.2f * v;
        m = fmaxf(m, v);
    }
    float den = 0.f;
    for (int idx = start; idx < end; ++idx) {
        int e = ids[idx];
        int s = (e < E) ? ei[e] : n;
        if ((unsigned)s >= (unsigned)N) s = n;
        float v = als[s * H + h] + aldn;
        v = v > 0.f ? v : 0.2f * v;
        den += expf(v - m);
    }
    mv[i] = m;
    dinv[i] = 1.0f / (den + EPS);
}

// ---------------------- per-(edge,head) alpha ----------------------
template <int H>
__global__ void alpha_kernel(const int* __restrict__ ei,
                             const float* __restrict__ als,
                             const float* __restrict__ ald,
                             const float* __restrict__ mv,
                             const float* __restrict__ dinv,
                             float* __restrict__ escr, int E, int N) {
    int i = blockIdx.x * blockDim.x + threadIdx.x;
    if (i >= (E + N) * H) return;
    int e = i / H, h = i % H;
    int s, d;
    if (e < E) {
        s = ei[e];
        d = ei[E + e];
        if ((unsigned)d >= (unsigned)N) { escr[i] = 0.f; return; }
        if ((unsigned)s >= (unsigned)N) s = d;
    } else {
        s = d = e - E;
    }
    float v = als[s * H + h] + ald[d * H + h];
    v = v > 0.f ? v : 0.2f * v;
    escr[i] = expf(v - mv[d * H + h]) * dinv[d * H + h];
}

// ---------------------- single-pass aggregation, ushort4 ----------------------
template <int H, int C>
__global__ void agg_kernel4(const unsigned short* __restrict__ hin,
                            const float* __restrict__ escr,
                            const int* __restrict__ rowst,
                            const int* __restrict__ ids,
                            const int* __restrict__ ei,
                            const float* __restrict__ bias,
                            unsigned short* __restrict__ out, int E, int N) {
    constexpr int HC = H * C;
    int n = blockIdx.x;
    int t = threadIdx.x;  // HC/4 threads
    int c = t * 4;
    int hh = c / C;
    int start = rowst[n], end = rowst[n + 1];
    float a0 = 0.f, a1 = 0.f, a2 = 0.f, a3 = 0.f;
    for (int idx = start; idx < end; ++idx) {
        int e = ids[idx];
        int s = (e < E) ? ei[e] : n;
        if ((unsigned)s >= (unsigned)N) s = n;
        float a = escr[(size_t)e * H + hh];
        ushort4 u = *(const ushort4*)(hin + (size_t)s * HC + c);
        a0 += a * b2f(u.x);
        a1 += a * b2f(u.y);
        a2 += a * b2f(u.z);
        a3 += a * b2f(u.w);
    }
    float v0 = a0 + bias[c], v1 = a1 + bias[c + 1];
    float v2 = a2 + bias[c + 2], v3 = a3 + bias[c + 3];
    ushort4 o;
    o.x = f2b(v0 > 0.f ? v0 : 0.01f * v0);
    o.y = f2b(v1 > 0.f ? v1 : 0.01f * v1);
    o.z = f2b(v2 > 0.f ? v2 : 0.01f * v2);
    o.w = f2b(v3 > 0.f ? v3 : 0.01f * v3);
    *(ushort4*)&out[(size_t)n * HC + c] = o;
}

// ushort2 variant for small HC (layer 3: HC=128, TPB=64)
template <int H, int C, int TPB>
__global__ void agg_kernel2(const unsigned short* __restrict__ hin,
                            const float* __restrict__ escr,
                            const int* __restrict__ rowst,
                            const int* __restrict__ ids,
                            const int* __restrict__ ei,
                            const float* __restrict__ bias,
                            unsigned short* __restrict__ out, int E, int N) {
    constexpr int HC = H * C;
    int n = blockIdx.x;
    int t = threadIdx.x;
    int c = t * 2;
    int hh = c / C;
    int start = rowst[n], end = rowst[n + 1];
    float a0 = 0.f, a1 = 0.f;
    for (int idx = start; idx < end; ++idx) {
        int e = ids[idx];
        int s = (e < E) ? ei[e] : n;
        if ((unsigned)s >= (unsigned)N) s = n;
        float a = escr[(size_t)e * H + hh];
        ushort2 u = *(const ushort2*)(hin + (size_t)s * HC + c);
        a0 += a * b2f(u.x);
        a1 += a * b2f(u.y);
    }
    float v0 = a0 + bias[c], v1 = a1 + bias[c + 1];
    ushort2 o;
    o.x = f2b(v0 > 0.f ? v0 : 0.01f * v0);
    o.y = f2b(v1 > 0.f ? v1 : 0.01f * v1);
    *(ushort2*)&out[(size_t)n * HC + c] = o;
}

// ---------------------- parallel mean-pool + head ----------------------
__global__ void pool_init_kernel(float* pool, int GC) {
    int i = blockIdx.x * blockDim.x + threadIdx.x;
    if (i < GC) pool[i] = 0.f;
}

__global__ void pool_partial_kernel(const unsigned short* __restrict__ h3,
                                    const int* __restrict__ batch,
                                    float* __restrict__ pool, int N, int G) {
    int lo = blockIdx.x * 128;
    int hi = lo + 128;
    if (hi > N) hi = N;
    if (lo >= N) return;
    int t = threadIdx.x;  // 128
    int cur = batch[lo];
    float acc = 0.f;
    for (int n = lo; n < hi; n++) {
        int g = batch[n];
        if (g != cur) {
            if ((unsigned)cur < (unsigned)G) atomicAdd(&pool[cur * 128 + t], acc);
            acc = 0.f;
            cur = g;
        }
        acc += b2f(h3[(size_t)n * 128 + t]);
    }
    if ((unsigned)cur < (unsigned)G) atomicAdd(&pool[cur * 128 + t], acc);
}

__global__ void head_kernel(const float* __restrict__ pool,
                            const int* __restrict__ batch,
                            const float* __restrict__ Wout,
                            const float* __restrict__ bout,
                            float* __restrict__ out, int N) {
    int g = blockIdx.x;
    int t = threadIdx.x;  // 128
    int lo, hi;
    {
        int a = 0, b = N;
        while (a < b) { int mid = (a + b) >> 1; if (batch[mid] < g) a = mid + 1; else b = mid; }
        lo = a;
        a = lo; b = N;
        while (a < b) { int mid = (a + b) >> 1; if (batch[mid] < g + 1) a = mid + 1; else b = mid; }
        hi = a;
    }
    float c = (float)(hi - lo);
    c = c > 1.f ? c : 1.f;
    float v = (pool[g * 128 + t] / c) * Wout[t];
    for (int o = 32; o; o >>= 1) v += __shfl_xor(v, o);
    __shared__ float partial[2];
    if ((t & 63) == 0) partial[t >> 6] = v;
    __syncthreads();
    if (t == 0) out[g] = partial[0] + partial[1] + bout[0];
}

// ---------------------------- host orchestration ----------------------------
extern "C" void kernel_launch(void* const* d_in, const int* in_sizes, int n_in,
                              void* d_out, int out_size, void* d_ws,
                              size_t ws_size, hipStream_t stream) {
    const float* x = (const float*)d_in[0];
    const int* ei = (const int*)d_in[1];
    const int* batch = (const int*)d_in[2];
    const float* W1 = (const float*)d_in[3];
    const float* a1s = (const float*)d_in[4];
    const float* a1d = (const float*)d_in[5];
    const float* b1 = (const float*)d_in[6];
    const float* W2 = (const float*)d_in[7];
    const float* a2s = (const float*)d_in[8];
    const float* a2d = (const float*)d_in[9];
    const float* b2 = (const float*)d_in[10];
    const float* W3 = (const float*)d_in[11];
    const float* a3s = (const float*)d_in[12];
    const float* a3d = (const float*)d_in[13];
    const float* b3 = (const float*)d_in[14];
    const float* Wout = (const float*)d_in[15];
    const float* bout = (const float*)d_in[16];
    float* out = (float*)d_out;

    const int N = in_sizes[0] / 11;
    const int E = in_sizes[1] / 2;
    const int Etot = E + N;
    const int G = out_size;
    const int NB = (N + 255) / 256;

    char* ws = (char*)d_ws;
    size_t off = 0;
    auto alloc = [&](size_t bytes) -> void* {
        void* p = ws + off;
        off += (bytes + 255) & ~(size_t)255;
        return p;
    };
    unsigned short* buf1 = (unsigned short*)alloc((size_t)N * 1024 * 2);  // h
    unsigned short* buf2 = (unsigned short*)alloc((size_t)N * 1024 * 2);  // out
    float* als = (float*)alloc((size_t)N * 8 * 4);
    float* ald = (float*)alloc((size_t)N * 8 * 4);
    float* mv = (float*)alloc((size_t)N * 8 * 4);
    float* dinv = (float*)alloc((size_t)N * 8 * 4);
    float* escr = (float*)alloc((size_t)Etot * 8 * 4);
    int* rowst = (int*)alloc((size_t)(N + 1) * 4);
    int* cursor = (int*)alloc((size_t)N * 4);
    int* ids = (int*)alloc((size_t)Etot * 4);
    int* deg = (int*)alloc((size_t)N * 4);
    int* bsum = (int*)alloc((size_t)NB * 4);
    int* boff = (int*)alloc((size_t)NB * 4);
    float* pool = (float*)alloc((size_t)G * 128 * 4);
    unsigned short* aggx = (unsigned short*)alloc((size_t)N * 128 * 2);
    unsigned short* w1bd = (unsigned short*)alloc((size_t)1024 * 128 * 2);
    unsigned short* wt2 = (unsigned short*)alloc((size_t)1024 * 512 * 2);
    unsigned short* wt3 = (unsigned short*)alloc((size_t)512 * 128 * 2);
    float* w_as = (float*)alloc(8 * 16 * 4);
    float* w_ad = (float*)alloc(8 * 16 * 4);

    int nb = (N + 255) / 256;
    int eb = (E + 255) / 256;

    // ---- CSR by dst (self-loop id = E+n at row head) ----
    init_deg_kernel<<<nb, 256, 0, stream>>>(deg, N);
    hist_kernel<<<eb, 256, 0, stream>>>(ei, E, N, deg);
    scan_block_kernel<<<NB, 256, 0, stream>>>(deg, rowst, bsum, N);
    scan_top_kernel<<<1, 64, 0, stream>>>(bsum, boff, NB);
    scan_add_kernel<<<NB, 256, 0, stream>>>(rowst, boff, N);
    selfloop_kernel<<<nb, 256, 0, stream>>>(rowst, ids, cursor, N, E);
    scatter_kernel<<<eb, 256, 0, stream>>>(ei, E, N, cursor, ids);

    // ---- weight prep ----
    wa1_kernel<<<1, 128, 0, stream>>>(W1, a1s, a1d, w_as, w_ad);
    w1bd_kernel<<<(1024 * 128 + 255) / 256, 256, 0, stream>>>(W1, w1bd);
    transpose_w_kernel<<<(1024 * 512 + 255) / 256, 256, 0, stream>>>(W2, wt2,
                                                                     1024, 512);
    transpose_w_kernel<<<(512 * 128 + 255) / 256, 256, 0, stream>>>(W3, wt3,
                                                                    512, 128);

    // ---- Layer 1 (linearity trick: aggregate x, then project) ----
    al1_kernel<<<(N * 8 + 255) / 256, 256, 0, stream>>>(x, w_as, w_ad, als, ald,
                                                        N);
    mden_kernel<8><<<(N * 8 + 255) / 256, 256, 0, stream>>>(als, ald, rowst, ids,
                                                            ei, mv, dinv, E, N);
    alpha_kernel<8><<<(Etot * 8 + 255) / 256, 256, 0, stream>>>(ei, als, ald, mv,
                                                                dinv, escr, E, N);
    aggx_kernel<<<N, 128, 0, stream>>>(x, escr, rowst, ids, ei, aggx, E, N);
    gemm_mfma<true><<<dim3(1024 / 128, (N + 127) / 128), 256, 0, stream>>>(
        aggx, w1bd, buf2, b1, N, 1024, 128);  // out1 = leaky01(. + b1)

    // ---- Layer 2: out1 [N,1024] @ W2 -> h2=buf1 [N,512]; H=8,C=64 ----
    gemm_mfma<false><<<dim3(512 / 128, (N + 127) / 128), 256, 0, stream>>>(
        buf2, wt2, buf1, nullptr, N, 512, 1024);
    al_kernel<<<(N * 8 + 3) / 4, 256, 0, stream>>>(buf1, a2s, a2d, als, ald,
                                                   N * 8, 8, 64);
    mden_kernel<8><<<(N * 8 + 255) / 256, 256, 0, stream>>>(als, ald, rowst, ids,
                                                            ei, mv, dinv, E, N);
    alpha_kernel<8><<<(Etot * 8 + 255) / 256, 256, 0, stream>>>(ei, als, ald, mv,
                                                                dinv, escr, E, N);
    agg_kernel4<8, 64><<<N, 128, 0, stream>>>(buf1, escr, rowst, ids, ei, b2,
                                              buf2, E, N);

    // ---- Layer 3: out2 [N,512] @ W3 -> h3=buf1 [N,128]; H=4,C=32 ----
    gemm_mfma<false><<<dim3(128 / 128, (N + 127) / 128), 256, 0, stream>>>(
        buf2, wt3, buf1, nullptr, N, 128, 512);
    al_kernel<<<(N * 4 + 3) / 4, 256, 0, stream>>>(buf1, a3s, a3d, als, ald,
                                                   N * 4, 4, 32);
    mden_kernel<4><<<(N * 4 + 255) / 256, 256, 0, stream>>>(als, ald, rowst, ids,
                                                            ei, mv, dinv, E, N);
    alpha_kernel<4><<<(Etot * 4 + 255) / 256, 256, 0, stream>>>(ei, als, ald, mv,
                                                                dinv, escr, E, N);
    agg_kernel2<4, 32, 64><<<N, 64, 0, stream>>>(buf1, escr, rowst, ids, ei, b3,
                                                 buf2, E, N);

    // ---- parallel mean-pool + head ----
    pool_init_kernel<<<(G * 128 + 255) / 256, 256, 0, stream>>>(pool, G * 128);
    pool_partial_kernel<<<(N + 127) / 128, 128, 0, stream>>>(buf2, batch, pool,
                                                             N, G);
    head_kernel<<<G, 128, 0, stream>>>(pool, batch, Wout, bout, out, N);
}

// Round 11
// 674.802 us; speedup vs baseline: 3.7865x; 1.0315x over previous
//
#include <hip/hip_runtime.h>

#define EPS 1e-16f

typedef __attribute__((ext_vector_type(8))) short short8;
typedef __attribute__((ext_vector_type(4))) float f32x4;

// ---------- bf16 <-> fp32 (internal storage only) ----------
__device__ __forceinline__ float b2f(unsigned short u) {
    return __uint_as_float(((unsigned)u) << 16);
}
__device__ __forceinline__ unsigned short f2b(float f) {
    unsigned u = __float_as_uint(f);
    u += 0x7fffu + ((u >> 16) & 1u);  // round-to-nearest-even
    return (unsigned short)(u >> 16);
}

// ---------------------------- CSR build ----------------------------
__global__ void init_deg_kernel(int* deg, int N) {
    int i = blockIdx.x * blockDim.x + threadIdx.x;
    if (i < N) deg[i] = 1;  // self-loop
}

__global__ void hist_kernel(const int* __restrict__ ei, int E, int N, int* deg) {
    int e = blockIdx.x * blockDim.x + threadIdx.x;
    if (e < E) {
        int d = ei[E + e];
        if ((unsigned)d < (unsigned)N) atomicAdd(&deg[d], 1);
    }
}

__global__ void scan_block_kernel(const int* __restrict__ deg,
                                  int* __restrict__ rowst,
                                  int* __restrict__ bsum, int N) {
    __shared__ int s[256];
    int t = threadIdx.x, b = blockIdx.x;
    int i = b * 256 + t;
    s[t] = (i < N) ? deg[i] : 0;
    __syncthreads();
    for (int o = 1; o < 256; o <<= 1) {
        int a = (t >= o) ? s[t - o] : 0;
        __syncthreads();
        s[t] += a;
        __syncthreads();
    }
    if (i < N) rowst[i + 1] = s[t];
    if (t == 255) bsum[b] = s[255];
}

__global__ void scan_top_kernel(const int* __restrict__ bsum,
                                int* __restrict__ boff, int NB) {
    __shared__ int psum[65];
    int t = threadIdx.x;  // 64
    int chunk = (NB + 63) / 64;
    int lo = t * chunk, hi = lo + chunk;
    if (lo > NB) lo = NB;
    if (hi > NB) hi = NB;
    int s = 0;
    for (int i = lo; i < hi; i++) s += bsum[i];
    psum[t + 1] = s;
    __syncthreads();
    if (t == 0) {
        psum[0] = 0;
        for (int i = 1; i <= 64; i++) psum[i] += psum[i - 1];
    }
    __syncthreads();
    int run = psum[t];
    for (int i = lo; i < hi; i++) {
        boff[i] = run;  // exclusive
        run += bsum[i];
    }
}

__global__ void scan_add_kernel(int* __restrict__ rowst,
                                const int* __restrict__ boff, int N) {
    int i = blockIdx.x * 256 + threadIdx.x;
    if (i == 0) rowst[0] = 0;
    if (i < N) rowst[i + 1] += boff[blockIdx.x];
}

__global__ void selfloop_kernel(const int* __restrict__ rowst, int* ids,
                                int* cursor, int N, int E) {
    int n = blockIdx.x * blockDim.x + threadIdx.x;
    if (n < N) {
        ids[rowst[n]] = E + n;  // self-loop edge id
        cursor[n] = rowst[n] + 1;
    }
}

__global__ void scatter_kernel(const int* __restrict__ ei, int E, int N,
                               int* cursor, int* ids) {
    int e = blockIdx.x * blockDim.x + threadIdx.x;
    if (e < E) {
        int d = ei[E + e];
        if ((unsigned)d < (unsigned)N) {
            int p = atomicAdd(&cursor[d], 1);
            ids[p] = e;
        }
    }
}

// ---------------------------- layer-1 specials ----------------------------
__global__ void wa1_kernel(const float* __restrict__ W1,
                           const float* __restrict__ a1s,
                           const float* __restrict__ a1d,
                           float* __restrict__ w_as, float* __restrict__ w_ad) {
    int t = threadIdx.x;  // 128; active t<88
    if (t >= 88) return;
    int h = t / 11, k = t % 11;
    float s = 0.f, d = 0.f;
    for (int c = 0; c < 128; c++) {
        float w = W1[k * 1024 + h * 128 + c];
        s += w * a1s[h * 128 + c];
        d += w * a1d[h * 128 + c];
    }
    w_as[h * 16 + k] = s;
    w_ad[h * 16 + k] = d;
}

__global__ void al1_kernel(const float* __restrict__ x,
                           const float* __restrict__ w_as,
                           const float* __restrict__ w_ad,
                           float* __restrict__ als, float* __restrict__ ald,
                           int N) {
    int i = blockIdx.x * blockDim.x + threadIdx.x;
    if (i >= N * 8) return;
    int n = i >> 3, h = i & 7;
    float s = 0.f, d = 0.f;
#pragma unroll
    for (int k = 0; k < 11; k++) {
        float xv = x[n * 11 + k];
        s += xv * w_as[h * 16 + k];
        d += xv * w_ad[h * 16 + k];
    }
    als[i] = s;
    ald[i] = d;
}

__global__ void aggx_kernel(const float* __restrict__ x,
                            const float* __restrict__ escr,
                            const int* __restrict__ rowst,
                            const int* __restrict__ ids,
                            const int* __restrict__ ei,
                            unsigned short* __restrict__ A2, int E, int N) {
    int n = blockIdx.x;
    int t = threadIdx.x;  // 128
    int h = t >> 4, k = t & 15;
    int start = rowst[n], end = rowst[n + 1];
    float acc = 0.f;
    for (int idx = start; idx < end; ++idx) {
        int e = ids[idx];
        int s = (e < E) ? ei[e] : n;
        if ((unsigned)s >= (unsigned)N) s = n;
        float a = escr[(size_t)e * 8 + h];
        float xv = (k < 11) ? x[s * 11 + k] : 0.f;
        acc += a * xv;
    }
    A2[(size_t)n * 128 + t] = f2b(acc);
}

__global__ void w1bd_kernel(const float* __restrict__ W1,
                            unsigned short* __restrict__ Bt) {
    int i = blockIdx.x * blockDim.x + threadIdx.x;
    if (i >= 1024 * 128) return;
    int n = i >> 7, kk = i & 127;
    int h = kk >> 4, k = kk & 15;
    float v = (h == (n >> 7) && k < 11) ? W1[k * 1024 + n] : 0.f;
    Bt[i] = f2b(v);
}

// ---------------------------- GEMM prep ----------------------------
__global__ void transpose_w_kernel(const float* __restrict__ W,
                                   unsigned short* __restrict__ Wt, int K, int N) {
    int i = blockIdx.x * blockDim.x + threadIdx.x;
    if (i >= K * N) return;
    int k = i / N, n = i % N;
    Wt[(size_t)n * K + k] = f2b(W[i]);
}

// MFMA GEMM: C[M,N] = A[M,K] * Bt[N,K]^T. bf16 in/out, fp32 accum.
// BM=BN=128, BK=32; 4 waves each own a 64x64 quadrant. N%128==0, K%32==0.
// gridDim.x = N/128 (power of 2), gridDim.y = ceil(M/128/8)*8.
// XCD swizzle: same-M blocks (n=0..NX-1) land on the SAME XCD (b%8) so the
// A-panel (256KB) stays in that XCD's 4MB L2 across all col-tiles.
template <bool EPI>
__global__ __launch_bounds__(256) void gemm_mfma(
    const unsigned short* __restrict__ A, const unsigned short* __restrict__ Bt,
    unsigned short* __restrict__ C, const float* __restrict__ bias, int M,
    int N, int K) {
    int NX = gridDim.x;
    int bid = blockIdx.y * NX + blockIdx.x;
    int win = bid & (8 * NX - 1);
    int mg = bid / (8 * NX);
    int m_t = mg * 8 + (win & 7);
    int n_t = win >> 3;
    int bm = m_t * 128, bn = n_t * 128;
    if (bm >= M) return;

    __shared__ unsigned short As[128][40];  // [m][k], +8 pad
    __shared__ unsigned short Bs[128][40];  // [n][k], +8 pad
    int t = threadIdx.x;
    int w = t >> 6, lane = t & 63;
    int quad = lane >> 4, l16 = lane & 15;
    int wr = (w >> 1) * 64, wc = (w & 1) * 64;
    f32x4 acc[4][4] = {};
    for (int k0 = 0; k0 < K; k0 += 32) {
#pragma unroll
        for (int rep = 0; rep < 2; rep++) {
            int linear = rep * 2048 + t * 8;
            int row = linear >> 5, col = linear & 31;
            int grow = bm + row;
            uint4 v = make_uint4(0, 0, 0, 0);
            if (grow < M) v = *(const uint4*)(A + (size_t)grow * K + k0 + col);
            *(uint4*)&As[row][col] = v;
            uint4 bv = *(const uint4*)(Bt + (size_t)(bn + row) * K + k0 + col);
            *(uint4*)&Bs[row][col] = bv;
        }
        __syncthreads();
        short8 a[4], b[4];
#pragma unroll
        for (int mi = 0; mi < 4; mi++)
            a[mi] = *(const short8*)&As[wr + mi * 16 + l16][quad * 8];
#pragma unroll
        for (int ni = 0; ni < 4; ni++)
            b[ni] = *(const short8*)&Bs[wc + ni * 16 + l16][quad * 8];
#pragma unroll
        for (int mi = 0; mi < 4; mi++)
#pragma unroll
            for (int ni = 0; ni < 4; ni++)
                acc[mi][ni] = __builtin_amdgcn_mfma_f32_16x16x32_bf16(
                    a[mi], b[ni], acc[mi][ni], 0, 0, 0);
        __syncthreads();
    }
#pragma unroll
    for (int mi = 0; mi < 4; mi++) {
#pragma unroll
        for (int r = 0; r < 4; r++) {
            int row = bm + wr + mi * 16 + quad * 4 + r;
            if (row < M) {
#pragma unroll
                for (int ni = 0; ni < 4; ni++) {
                    int col = bn + wc + ni * 16 + l16;
                    float v = acc[mi][ni][r];
                    if (EPI) {
                        v += bias[col];
                        v = v > 0.f ? v : 0.01f * v;
                    }
                    C[(size_t)row * N + col] = f2b(v);
                }
            }
        }
    }
}

// ---------------------------- attention logits ----------------------------
__global__ void al_kernel(const unsigned short* __restrict__ h,
                          const float* __restrict__ a_s,
                          const float* __restrict__ a_d, float* __restrict__ als,
                          float* __restrict__ ald, int NH, int H, int C) {
    int wave = (int)((blockIdx.x * blockDim.x + threadIdx.x) >> 6);
    int lane = threadIdx.x & 63;
    if (wave >= NH) return;
    int n = wave / H, hh = wave % H;
    const unsigned short* hp = h + (size_t)n * H * C + (size_t)hh * C;
    const float* as = a_s + hh * C;
    const float* ad = a_d + hh * C;
    float s = 0.f, d = 0.f;
    for (int c = lane; c < C; c += 64) {
        float v = b2f(hp[c]);
        s += v * as[c];
        d += v * ad[c];
    }
    for (int o = 32; o; o >>= 1) {
        s += __shfl_xor(s, o);
        d += __shfl_xor(d, o);
    }
    if (lane == 0) { als[wave] = s; ald[wave] = d; }
}

// ---------------- softmax: per-(n,h) max & inv-denominator ----------------
template <int H>
__global__ void mden_kernel(const float* __restrict__ als,
                            const float* __restrict__ ald,
                            const int* __restrict__ rowst,
                            const int* __restrict__ ids,
                            const int* __restrict__ ei, float* __restrict__ mv,
                            float* __restrict__ dinv, int E, int N) {
    int i = blockIdx.x * blockDim.x + threadIdx.x;
    if (i >= N * H) return;
    int n = i / H, h = i % H;
    float aldn = ald[i];
    int start = rowst[n], end = rowst[n + 1];
    float v0 = als[n * H + h] + aldn;  // self-loop logit (always present)
    float m = v0 > 0.f ? v0 : 0.2f * v0;
    for (int idx = start; idx < end; ++idx) {
        int e = ids[idx];
        int s = (e < E) ? ei[e] : n;
        if ((unsigned)s >= (unsigned)N) s = n;
        float v = als[s * H + h] + aldn;
        v = v > 0.f ? v : 0.2f * v;
        m = fmaxf(m, v);
    }
    float den = 0.f;
    for (int idx = start; idx < end; ++idx) {
        int e = ids[idx];
        int s = (e < E) ? ei[e] : n;
        if ((unsigned)s >= (unsigned)N) s = n;
        float v = als[s * H + h] + aldn;
        v = v > 0.f ? v : 0.2f * v;
        den += expf(v - m);
    }
    mv[i] = m;
    dinv[i] = 1.0f / (den + EPS);
}

// ---------------------- per-(edge,head) alpha ----------------------
template <int H>
__global__ void alpha_kernel(const int* __restrict__ ei,
                             const float* __restrict__ als,
                             const float* __restrict__ ald,
                             const float* __restrict__ mv,
                             const float* __restrict__ dinv,
                             float* __restrict__ escr, int E, int N) {
    int i = blockIdx.x * blockDim.x + threadIdx.x;
    if (i >= (E + N) * H) return;
    int e = i / H, h = i % H;
    int s, d;
    if (e < E) {
        s = ei[e];
        d = ei[E + e];
        if ((unsigned)d >= (unsigned)N) { escr[i] = 0.f; return; }
        if ((unsigned)s >= (unsigned)N) s = d;
    } else {
        s = d = e - E;
    }
    float v = als[s * H + h] + ald[d * H + h];
    v = v > 0.f ? v : 0.2f * v;
    escr[i] = expf(v - mv[d * H + h]) * dinv[d * H + h];
}

// ---------------------- single-pass aggregation, ushort4 ----------------------
template <int H, int C>
__global__ void agg_kernel4(const unsigned short* __restrict__ hin,
                            const float* __restrict__ escr,
                            const int* __restrict__ rowst,
                            const int* __restrict__ ids,
                            const int* __restrict__ ei,
                            const float* __restrict__ bias,
                            unsigned short* __restrict__ out, int E, int N) {
    constexpr int HC = H * C;
    int n = blockIdx.x;
    int t = threadIdx.x;  // HC/4 threads
    int c = t * 4;
    int hh = c / C;
    int start = rowst[n], end = rowst[n + 1];
    float a0 = 0.f, a1 = 0.f, a2 = 0.f, a3 = 0.f;
    for (int idx = start; idx < end; ++idx) {
        int e = ids[idx];
        int s = (e < E) ? ei[e] : n;
        if ((unsigned)s >= (unsigned)N) s = n;
        float a = escr[(size_t)e * H + hh];
        ushort4 u = *(const ushort4*)(hin + (size_t)s * HC + c);
        a0 += a * b2f(u.x);
        a1 += a * b2f(u.y);
        a2 += a * b2f(u.z);
        a3 += a * b2f(u.w);
    }
    float v0 = a0 + bias[c], v1 = a1 + bias[c + 1];
    float v2 = a2 + bias[c + 2], v3 = a3 + bias[c + 3];
    ushort4 o;
    o.x = f2b(v0 > 0.f ? v0 : 0.01f * v0);
    o.y = f2b(v1 > 0.f ? v1 : 0.01f * v1);
    o.z = f2b(v2 > 0.f ? v2 : 0.01f * v2);
    o.w = f2b(v3 > 0.f ? v3 : 0.01f * v3);
    *(ushort4*)&out[(size_t)n * HC + c] = o;
}

// ushort2 variant for small HC (layer 3: HC=128, TPB=64)
template <int H, int C, int TPB>
__global__ void agg_kernel2(const unsigned short* __restrict__ hin,
                            const float* __restrict__ escr,
                            const int* __restrict__ rowst,
                            const int* __restrict__ ids,
                            const int* __restrict__ ei,
                            const float* __restrict__ bias,
                            unsigned short* __restrict__ out, int E, int N) {
    constexpr int HC = H * C;
    int n = blockIdx.x;
    int t = threadIdx.x;
    int c = t * 2;
    int hh = c / C;
    int start = rowst[n], end = rowst[n + 1];
    float a0 = 0.f, a1 = 0.f;
    for (int idx = start; idx < end; ++idx) {
        int e = ids[idx];
        int s = (e < E) ? ei[e] : n;
        if ((unsigned)s >= (unsigned)N) s = n;
        float a = escr[(size_t)e * H + hh];
        ushort2 u = *(const ushort2*)(hin + (size_t)s * HC + c);
        a0 += a * b2f(u.x);
        a1 += a * b2f(u.y);
    }
    float v0 = a0 + bias[c], v1 = a1 + bias[c + 1];
    ushort2 o;
    o.x = f2b(v0 > 0.f ? v0 : 0.01f * v0);
    o.y = f2b(v1 > 0.f ? v1 : 0.01f * v1);
    *(ushort2*)&out[(size_t)n * HC + c] = o;
}

// ---------------------- parallel mean-pool + head ----------------------
__global__ void pool_init_kernel(float* pool, int GC) {
    int i = blockIdx.x * blockDim.x + threadIdx.x;
    if (i < GC) pool[i] = 0.f;
}

__global__ void pool_partial_kernel(const unsigned short* __restrict__ h3,
                                    const int* __restrict__ batch,
                                    float* __restrict__ pool, int N, int G) {
    int lo = blockIdx.x * 128;
    int hi = lo + 128;
    if (hi > N) hi = N;
    if (lo >= N) return;
    int t = threadIdx.x;  // 128
    int cur = batch[lo];
    float acc = 0.f;
    for (int n = lo; n < hi; n++) {
        int g = batch[n];
        if (g != cur) {
            if ((unsigned)cur < (unsigned)G) atomicAdd(&pool[cur * 128 + t], acc);
            acc = 0.f;
            cur = g;
        }
        acc += b2f(h3[(size_t)n * 128 + t]);
    }
    if ((unsigned)cur < (unsigned)G) atomicAdd(&pool[cur * 128 + t], acc);
}

__global__ void head_kernel(const float* __restrict__ pool,
                            const int* __restrict__ batch,
                            const float* __restrict__ Wout,
                            const float* __restrict__ bout,
                            float* __restrict__ out, int N) {
    int g = blockIdx.x;
    int t = threadIdx.x;  // 128
    int lo, hi;
    {
        int a = 0, b = N;
        while (a < b) { int mid = (a + b) >> 1; if (batch[mid] < g) a = mid + 1; else b = mid; }
        lo = a;
        a = lo; b = N;
        while (a < b) { int mid = (a + b) >> 1; if (batch[mid] < g + 1) a = mid + 1; else b = mid; }
        hi = a;
    }
    float c = (float)(hi - lo);
    c = c > 1.f ? c : 1.f;
    float v = (pool[g * 128 + t] / c) * Wout[t];
    for (int o = 32; o; o >>= 1) v += __shfl_xor(v, o);
    __shared__ float partial[2];
    if ((t & 63) == 0) partial[t >> 6] = v;
    __syncthreads();
    if (t == 0) out[g] = partial[0] + partial[1] + bout[0];
}

// ---------------------------- host orchestration ----------------------------
extern "C" void kernel_launch(void* const* d_in, const int* in_sizes, int n_in,
                              void* d_out, int out_size, void* d_ws,
                              size_t ws_size, hipStream_t stream) {
    const float* x = (const float*)d_in[0];
    const int* ei = (const int*)d_in[1];
    const int* batch = (const int*)d_in[2];
    const float* W1 = (const float*)d_in[3];
    const float* a1s = (const float*)d_in[4];
    const float* a1d = (const float*)d_in[5];
    const float* b1 = (const float*)d_in[6];
    const float* W2 = (const float*)d_in[7];
    const float* a2s = (const float*)d_in[8];
    const float* a2d = (const float*)d_in[9];
    const float* b2 = (const float*)d_in[10];
    const float* W3 = (const float*)d_in[11];
    const float* a3s = (const float*)d_in[12];
    const float* a3d = (const float*)d_in[13];
    const float* b3 = (const float*)d_in[14];
    const float* Wout = (const float*)d_in[15];
    const float* bout = (const float*)d_in[16];
    float* out = (float*)d_out;

    const int N = in_sizes[0] / 11;
    const int E = in_sizes[1] / 2;
    const int Etot = E + N;
    const int G = out_size;
    const int NB = (N + 255) / 256;
    const int MT = ((N + 127) / 128 + 7) / 8 * 8;  // M-tiles padded to x8

    char* ws = (char*)d_ws;
    size_t off = 0;
    auto alloc = [&](size_t bytes) -> void* {
        void* p = ws + off;
        off += (bytes + 255) & ~(size_t)255;
        return p;
    };
    unsigned short* buf1 = (unsigned short*)alloc((size_t)N * 1024 * 2);  // h
    unsigned short* buf2 = (unsigned short*)alloc((size_t)N * 1024 * 2);  // out
    float* als = (float*)alloc((size_t)N * 8 * 4);
    float* ald = (float*)alloc((size_t)N * 8 * 4);
    float* mv = (float*)alloc((size_t)N * 8 * 4);
    float* dinv = (float*)alloc((size_t)N * 8 * 4);
    float* escr = (float*)alloc((size_t)Etot * 8 * 4);
    int* rowst = (int*)alloc((size_t)(N + 1) * 4);
    int* cursor = (int*)alloc((size_t)N * 4);
    int* ids = (int*)alloc((size_t)Etot * 4);
    int* deg = (int*)alloc((size_t)N * 4);
    int* bsum = (int*)alloc((size_t)NB * 4);
    int* boff = (int*)alloc((size_t)NB * 4);
    float* pool = (float*)alloc((size_t)G * 128 * 4);
    unsigned short* aggx = (unsigned short*)alloc((size_t)N * 128 * 2);
    unsigned short* w1bd = (unsigned short*)alloc((size_t)1024 * 128 * 2);
    unsigned short* wt2 = (unsigned short*)alloc((size_t)1024 * 512 * 2);
    unsigned short* wt3 = (unsigned short*)alloc((size_t)512 * 128 * 2);
    float* w_as = (float*)alloc(8 * 16 * 4);
    float* w_ad = (float*)alloc(8 * 16 * 4);

    int nb = (N + 255) / 256;
    int eb = (E + 255) / 256;

    // ---- CSR by dst (self-loop id = E+n at row head) ----
    init_deg_kernel<<<nb, 256, 0, stream>>>(deg, N);
    hist_kernel<<<eb, 256, 0, stream>>>(ei, E, N, deg);
    scan_block_kernel<<<NB, 256, 0, stream>>>(deg, rowst, bsum, N);
    scan_top_kernel<<<1, 64, 0, stream>>>(bsum, boff, NB);
    scan_add_kernel<<<NB, 256, 0, stream>>>(rowst, boff, N);
    selfloop_kernel<<<nb, 256, 0, stream>>>(rowst, ids, cursor, N, E);
    scatter_kernel<<<eb, 256, 0, stream>>>(ei, E, N, cursor, ids);

    // ---- weight prep ----
    wa1_kernel<<<1, 128, 0, stream>>>(W1, a1s, a1d, w_as, w_ad);
    w1bd_kernel<<<(1024 * 128 + 255) / 256, 256, 0, stream>>>(W1, w1bd);
    transpose_w_kernel<<<(1024 * 512 + 255) / 256, 256, 0, stream>>>(W2, wt2,
                                                                     1024, 512);
    transpose_w_kernel<<<(512 * 128 + 255) / 256, 256, 0, stream>>>(W3, wt3,
                                                                    512, 128);

    // ---- Layer 1 (linearity trick: aggregate x, then project) ----
    al1_kernel<<<(N * 8 + 255) / 256, 256, 0, stream>>>(x, w_as, w_ad, als, ald,
                                                        N);
    mden_kernel<8><<<(N * 8 + 255) / 256, 256, 0, stream>>>(als, ald, rowst, ids,
                                                            ei, mv, dinv, E, N);
    alpha_kernel<8><<<(Etot * 8 + 255) / 256, 256, 0, stream>>>(ei, als, ald, mv,
                                                                dinv, escr, E, N);
    aggx_kernel<<<N, 128, 0, stream>>>(x, escr, rowst, ids, ei, aggx, E, N);
    gemm_mfma<true><<<dim3(8, MT), 256, 0, stream>>>(aggx, w1bd, buf2, b1, N,
                                                     1024, 128);

    // ---- Layer 2: out1 [N,1024] @ W2 -> h2=buf1 [N,512]; H=8,C=64 ----
    gemm_mfma<false><<<dim3(4, MT), 256, 0, stream>>>(buf2, wt2, buf1, nullptr,
                                                      N, 512, 1024);
    al_kernel<<<(N * 8 + 3) / 4, 256, 0, stream>>>(buf1, a2s, a2d, als, ald,
                                                   N * 8, 8, 64);
    mden_kernel<8><<<(N * 8 + 255) / 256, 256, 0, stream>>>(als, ald, rowst, ids,
                                                            ei, mv, dinv, E, N);
    alpha_kernel<8><<<(Etot * 8 + 255) / 256, 256, 0, stream>>>(ei, als, ald, mv,
                                                                dinv, escr, E, N);
    agg_kernel4<8, 64><<<N, 128, 0, stream>>>(buf1, escr, rowst, ids, ei, b2,
                                              buf2, E, N);

    // ---- Layer 3: out2 [N,512] @ W3 -> h3=buf1 [N,128]; H=4,C=32 ----
    gemm_mfma<false><<<dim3(1, MT), 256, 0, stream>>>(buf2, wt3, buf1, nullptr,
                                                      N, 128, 512);
    al_kernel<<<(N * 4 + 3) / 4, 256, 0, stream>>>(buf1, a3s, a3d, als, ald,
                                                   N * 4, 4, 32);
    mden_kernel<4><<<(N * 4 + 255) / 256, 256, 0, stream>>>(als, ald, rowst, ids,
                                                            ei, mv, dinv, E, N);
    alpha_kernel<4><<<(Etot * 4 + 255) / 256, 256, 0, stream>>>(ei, als, ald, mv,
                                                                dinv, escr, E, N);
    agg_kernel2<4, 32, 64><<<N, 64, 0, stream>>>(buf1, escr, rowst, ids, ei, b3,
                                                 buf2, E, N);

    // ---- parallel mean-pool + head ----
    pool_init_kernel<<<(G * 128 + 255) / 256, 256, 0, stream>>>(pool, G * 128);
    pool_partial_kernel<<<(N + 127) / 128, 128, 0, stream>>>(buf2, batch, pool,
                                                             N, G);
    head_kernel<<<G, 128, 0, stream>>>(pool, batch, Wout, bout, out, N);
}